// Round 11
// baseline (276.870 us; speedup 1.0000x reference)
//
#include <hip/hip_runtime.h>
#include <hip/hip_fp16.h>
#include <math.h>

#define ALPHA_C 0.5f
#define BETA_C  0.5f
#define NPART   256
#define NQUART  4
#define NBKT    8
#define SCH     6250   // edges per scatter workgroup (LDS-resident chunk)

typedef _Float16 half8 __attribute__((ext_vector_type(8)));
typedef _Float16 half2v __attribute__((ext_vector_type(2)));
typedef float f32x4 __attribute__((ext_vector_type(4)));

// XOR row-swizzle: spreads a column access across 8 LDS bank-groups.
__device__ __forceinline__ int swz(int row, int byteoff) {
    return byteoff ^ ((row & 7) << 4);
}

// Exact degree histogram with NO global atomics (round-4 design).
__global__ __launch_bounds__(256) void k_hist(
        const int* __restrict__ eidx, unsigned int* __restrict__ scr,
        int N, int E, int Q, int Wd, int chunk) {
    const int s = blockIdx.x;
    const int role = blockIdx.y;
    const int dir = role & 1;
    const int q = role >> 1;
    extern __shared__ unsigned int lds[];          // Wd words
    for (int w = threadIdx.x; w < Wd; w += blockDim.x) lds[w] = 0;
    __syncthreads();
    const int base = q * Q;
    const int hi = min(N - base, Q);
    const int* __restrict__ arr = eidx + (size_t)dir * E;
    const int start = s * chunk;
    const int end = min(E, start + chunk);
    const int4* __restrict__ a4 = (const int4*)arr;
    const int v1 = end >> 2;
    for (int v = (start >> 2) + threadIdx.x; v < v1; v += blockDim.x) {
        int4 x = a4[v];
        int l;
        l = x.x - base; if ((unsigned)l < (unsigned)hi) atomicAdd(&lds[l >> 1], 1u << ((l & 1) * 16));
        l = x.y - base; if ((unsigned)l < (unsigned)hi) atomicAdd(&lds[l >> 1], 1u << ((l & 1) * 16));
        l = x.z - base; if ((unsigned)l < (unsigned)hi) atomicAdd(&lds[l >> 1], 1u << ((l & 1) * 16));
        l = x.w - base; if ((unsigned)l < (unsigned)hi) atomicAdd(&lds[l >> 1], 1u << ((l & 1) * 16));
    }
    for (int i = (v1 << 2) + threadIdx.x; i < end; i += blockDim.x) {
        int l = arr[i] - base;
        if ((unsigned)l < (unsigned)hi) atomicAdd(&lds[l >> 1], 1u << ((l & 1) * 16));
    }
    __syncthreads();
    unsigned int* __restrict__ dst = scr + ((size_t)role * gridDim.x + s) * Wd;
    for (int w = threadIdx.x; w < Wd; w += blockDim.x) dst[w] = lds[w];
}

// Per-chunk dst-bucket counts (no atomics beyond LDS; wave-ballot aggregated).
__global__ __launch_bounds__(256) void k_bcnt(
        const int* __restrict__ eidx, unsigned* __restrict__ wgcnt,
        int E, int BQ) {
    __shared__ unsigned cnt[NBKT];
    if (threadIdx.x < NBKT) cnt[threadIdx.x] = 0;
    __syncthreads();
    const int c0 = blockIdx.x * SCH;
    const int lim = min(E - c0, SCH);
    const int lane = threadIdx.x & 63;
    for (int it = 0; it * 256 < lim; ++it) {
        int i = it * 256 + threadIdx.x;
        unsigned bkt = NBKT;
        if (i < lim) bkt = (unsigned)eidx[E + c0 + i] / (unsigned)BQ;
#pragma unroll
        for (unsigned b = 0; b < NBKT; ++b) {
            unsigned long long m = __ballot(bkt == b);
            if (m && lane == (__ffsll((long long)m) - 1))
                atomicAdd(&cnt[b], (unsigned)__popcll(m));
        }
    }
    __syncthreads();
    if (threadIdx.x < NBKT) wgcnt[blockIdx.x * NBKT + threadIdx.x] = cnt[threadIdx.x];
}

// Fold slice histograms -> float degrees + sum-of-squares partials.
__global__ __launch_bounds__(256) void k_fold(
        const unsigned int* __restrict__ scr,
        float* __restrict__ deg_out, float* __restrict__ deg_in,
        float* __restrict__ partials, int N, int Q, int Wd, int S) {
    float so = 0.f, si = 0.f;
    for (int n = blockIdx.x * blockDim.x + threadIdx.x; n < N;
         n += gridDim.x * blockDim.x) {
        const int q = n / Q, l = n - q * Q;
        const int w = l >> 1, sh = (l & 1) * 16;
        const unsigned int* __restrict__ p0 = scr + ((size_t)(q * 2 + 0) * S) * Wd + w;
        const unsigned int* __restrict__ p1 = scr + ((size_t)(q * 2 + 1) * S) * Wd + w;
        unsigned int a = 0, b = 0;
        for (int s = 0; s < S; ++s) {
            a += (p0[(size_t)s * Wd] >> sh) & 0xFFFFu;
            b += (p1[(size_t)s * Wd] >> sh) & 0xFFFFu;
        }
        float fa = (float)a, fb = (float)b;
        deg_out[n] = fa;
        deg_in[n] = fb;
        so = fmaf(fa, fa, so);
        si = fmaf(fb, fb, si);
    }
#pragma unroll
    for (int off = 32; off; off >>= 1) {
        so += __shfl_xor(so, off);
        si += __shfl_xor(si, off);
    }
    __shared__ float sm[2][4];
    int lane = threadIdx.x & 63, w = threadIdx.x >> 6;
    if (lane == 0) { sm[0][w] = so; sm[1][w] = si; }
    __syncthreads();
    if (threadIdx.x == 0) {
        partials[blockIdx.x]         = sm[0][0] + sm[0][1] + sm[0][2] + sm[0][3];
        partials[NPART + blockIdx.x] = sm[1][0] + sm[1][1] + sm[1][2] + sm[1][3];
    }
}

// Norm finish + deterministic bucket scan (per-WG bases, global bases+counts).
__global__ __launch_bounds__(256) void k_finish(
        const float* __restrict__ partials, float* __restrict__ inv_nrm,
        const unsigned* __restrict__ wgcnt, unsigned* __restrict__ wgbase,
        unsigned* __restrict__ bmeta, int NWG) {
    int t = threadIdx.x;
    __shared__ unsigned sb[NBKT];
    if (t < NBKT && NWG > 0) {
        unsigned run = 0;
        for (int w = 0; w < NWG; ++w) {
            wgbase[w * NBKT + t] = run;
            run += wgcnt[w * NBKT + t];
        }
        sb[t] = run;
    }
    float so = partials[t], si = partials[NPART + t];
#pragma unroll
    for (int off = 32; off; off >>= 1) {
        so += __shfl_xor(so, off);
        si += __shfl_xor(si, off);
    }
    __shared__ float sm[2][4];
    int lane = t & 63, w = t >> 6;
    if (lane == 0) { sm[0][w] = so; sm[1][w] = si; }
    __syncthreads();
    if (t == 0) {
        float a = sm[0][0] + sm[0][1] + sm[0][2] + sm[0][3];
        float b = sm[1][0] + sm[1][1] + sm[1][2] + sm[1][3];
        inv_nrm[0] = (a > 0.f) ? rsqrtf(a) : 0.f;
        inv_nrm[1] = (b > 0.f) ? rsqrtf(b) : 0.f;
        if (NWG > 0) {
            unsigned acc = 0;
#pragma unroll
            for (int bb = 0; bb < NBKT; ++bb) {
                bmeta[bb] = acc;           // bucket base
                bmeta[NBKT + bb] = sb[bb]; // bucket count
                acc += sb[bb];
            }
        }
    }
}

// Stable deterministic scatter into dst-buckets. packed = s | (d_local<<17).
__global__ __launch_bounds__(256) void k_scatter(
        const int* __restrict__ eidx, const unsigned* __restrict__ wgbase,
        const unsigned* __restrict__ bmeta, unsigned* __restrict__ packed_sd,
        int* __restrict__ eidq, int E, int BQ) {
    __shared__ unsigned lsd[SCH];
    __shared__ unsigned char lb[SCH];
    __shared__ unsigned lcur[NBKT];
    const int w = blockIdx.x;
    const int c0 = w * SCH;
    const int lim = min(E - c0, SCH);
    const int tid = threadIdx.x, lane = tid & 63;
    if (tid < NBKT) lcur[tid] = bmeta[tid] + wgbase[w * NBKT + tid];
    for (int it = 0; it * 256 < lim; ++it) {
        int i = it * 256 + tid;
        if (i < lim) {
            unsigned s = (unsigned)eidx[c0 + i];
            unsigned d = (unsigned)eidx[E + c0 + i];
            unsigned b = d / (unsigned)BQ;
            lsd[i] = s | ((d - b * (unsigned)BQ) << 17);
            lb[i] = (unsigned char)b;
        }
    }
    __syncthreads();
    for (int it = 0; it * 256 < lim; ++it) {
        int i = it * 256 + tid;
        unsigned bkt = (i < lim) ? (unsigned)lb[i] : (unsigned)NBKT;
#pragma unroll
        for (unsigned b = 0; b < NBKT; ++b) {
            unsigned long long m = __ballot(bkt == b);
            if (!m) continue;
            int leader = __ffsll((long long)m) - 1;
            unsigned pbase = 0;
            if (lane == leader) pbase = atomicAdd(&lcur[b], (unsigned)__popcll(m));
            pbase = (unsigned)__shfl((int)pbase, leader);
            if (bkt == b) {
                unsigned pos = pbase + (unsigned)__popcll(m & ((1ULL << lane) - 1));
                packed_sd[pos] = lsd[i];
                eidq[pos] = c0 + i;
            }
        }
    }
}

// MFMA node precompute, LDS-staged (round-7 benched form, best measured).
__global__ __launch_bounds__(256) void k_nodes(
        const float* __restrict__ z_in, const float* __restrict__ z_out,
        const float* __restrict__ z_self,
        const float* __restrict__ W_in, const float* __restrict__ b_in,
        const float* __restrict__ W_out, const float* __restrict__ b_out,
        const float* __restrict__ deg_out, const float* __restrict__ deg_in,
        const float* __restrict__ inv_nrm,
        _Float16* __restrict__ P_src, _Float16* __restrict__ P_dst,
        float* __restrict__ s_src, float* __restrict__ s_dst, int N) {
    __shared__ _Float16 smem[16384];                 // 32 KB
    char* lzo = (char*)smem;                         // [64][64] f16, 8 KB
    char* lzi = (char*)smem + 8192;
    char* lwo = (char*)smem + 16384;                 // W^T [n=64][k=64] f16
    char* lwi = (char*)smem + 24576;
    char* lps = (char*)smem;                         // [64][128] f16 (aliases)
    char* lpd = (char*)smem + 16384;

    const int tid = threadIdx.x;
    const int lane = tid & 63;
    const int wid = tid >> 6;
    const int r = lane & 15, g = lane >> 4;
    const int base = blockIdx.x * 64;
    const int wrow = wid * 16;

    // ---- phase 1: stage z tiles and W^T into LDS (coalesced reads) ----
#pragma unroll
    for (int it = 0; it < 8; ++it) {
        int flat = it * 256 + tid;                   // [0, 2048)
        int row = flat >> 5;
        int c2 = (flat & 31) * 2;
        int grow = min(base + row, N - 1);
        const float* zr = z_out + (size_t)grow * 65;
        half2v ho = { (_Float16)zr[c2], (_Float16)zr[c2 + 1] };
        *(half2v*)(lzo + row * 128 + swz(row, c2 * 2)) = ho;
        const float* zr2 = z_in + (size_t)grow * 65;
        half2v hi = { (_Float16)zr2[c2], (_Float16)zr2[c2 + 1] };
        *(half2v*)(lzi + row * 128 + swz(row, c2 * 2)) = hi;
    }
#pragma unroll
    for (int it = 0; it < 16; ++it) {
        int flat = it * 256 + tid;                   // [0, 4096)
        int k = flat >> 6, n = flat & 63;
        *(_Float16*)(lwo + n * 128 + swz(n, k * 2)) = (_Float16)W_out[k * 64 + n];
        *(_Float16*)(lwi + n * 128 + swz(n, k * 2)) = (_Float16)W_in [k * 64 + n];
    }
    half8 bO[2], bI[2];
#pragma unroll
    for (int s = 0; s < 2; ++s)
#pragma unroll
        for (int j = 0; j < 8; ++j) {
            int k = 32 * s + 8 * g + j;
            bO[s][j] = (r == 0) ? (_Float16)b_out[k] : (_Float16)0.f;
            bI[s][j] = (r == 0) ? (_Float16)b_in [k] : (_Float16)0.f;
        }
    __syncthreads();

    // ---- phase 2: fragments from LDS + MFMA ----
    half8 AO[2], AI[2];
#pragma unroll
    for (int s = 0; s < 2; ++s) {
        int arow = wrow + r;
        int off = arow * 128 + swz(arow, s * 64 + g * 16);
        AO[s] = *(half8*)(lzo + off);
        AI[s] = *(half8*)(lzi + off);
    }
    f32x4 aO[4], aI[4], abO = (f32x4)0.f, abI = (f32x4)0.f;
#pragma unroll
    for (int t = 0; t < 4; ++t) { aO[t] = (f32x4)0.f; aI[t] = (f32x4)0.f; }
#pragma unroll
    for (int s = 0; s < 2; ++s) {
#pragma unroll
        for (int t = 0; t < 4; ++t) {
            int n = 16 * t + r;
            int off = n * 128 + swz(n, s * 64 + g * 16);
            half8 BO = *(half8*)(lwo + off);
            aO[t] = __builtin_amdgcn_mfma_f32_16x16x32_f16(AO[s], BO, aO[t], 0, 0, 0);
            half8 BI = *(half8*)(lwi + off);
            aI[t] = __builtin_amdgcn_mfma_f32_16x16x32_f16(AI[s], BI, aI[t], 0, 0, 0);
        }
        abO = __builtin_amdgcn_mfma_f32_16x16x32_f16(AO[s], bO[s], abO, 0, 0, 0);
        abI = __builtin_amdgcn_mfma_f32_16x16x32_f16(AI[s], bI[s], abI, 0, 0, 0);
    }
    __syncthreads();   // lz/lw dead; lp aliases them

    // ---- phase 3: results + z_self into swizzled LDS P-tiles ----
#pragma unroll
    for (int t = 0; t < 4; ++t)
#pragma unroll
        for (int rr = 0; rr < 4; ++rr) {
            int lrow = wrow + 4 * g + rr;
            int col2 = (16 * t + r) * 2;
            *(_Float16*)(lps + lrow * 256 + swz(lrow, col2)) = (_Float16)aO[t][rr];
            *(_Float16*)(lpd + lrow * 256 + swz(lrow, 128 + col2)) = (_Float16)aI[t][rr];
        }
#pragma unroll
    for (int it = 0; it < 8; ++it) {
        int flat = it * 256 + tid;
        int row = flat >> 5;
        int c2 = (flat & 31) * 2;
        int grow = min(base + row, N - 1);
        float2 v = *(const float2*)(z_self + (size_t)grow * 64 + c2);
        half2v h = { (_Float16)v.x, (_Float16)v.y };
        *(half2v*)(lps + row * 256 + swz(row, 128 + c2 * 2)) = h;   // P_src[,64:]
        *(half2v*)(lpd + row * 256 + swz(row, c2 * 2)) = h;         // P_dst[,:64]
    }
    if (r == 0) {
        const float i0 = inv_nrm[0], i1 = inv_nrm[1];
#pragma unroll
        for (int rr = 0; rr < 4; ++rr) {
            int m = base + wrow + 4 * g + rr;
            if (m < N) {
                s_src[m] = BETA_C * fmaf(deg_out[m], i0, z_out[(size_t)m * 65 + 64])
                         + ALPHA_C * abO[rr];
                s_dst[m] = BETA_C * fmaf(deg_in[m],  i1, z_in [(size_t)m * 65 + 64])
                         + ALPHA_C * abI[rr];
            }
        }
    }
    __syncthreads();

    // ---- phase 4: coalesced 16B/lane flush to global ----
#pragma unroll
    for (int it = 0; it < 4; ++it) {
        int lrow = it * 16 + (tid >> 4);
        int seg = tid & 15;
        int m = base + lrow;
        if (m < N) {
            half8 v = *(half8*)(lps + lrow * 256 + swz(lrow, seg * 16));
            *(half8*)(P_src + (size_t)m * 128 + seg * 8) = v;
            half8 v2 = *(half8*)(lpd + lrow * 256 + swz(lrow, seg * 16));
            *(half8*)(P_dst + (size_t)m * 128 + seg * 8) = v2;
        }
    }
}

// Bucketed edge kernel: bucket = blockIdx%8 -> XCD-pinned dst slice (3.2MB,
// L2-resident). 16 lanes per two edges; fdot2; grid-stride within bucket.
__global__ __launch_bounds__(256) void k_edges2(
        const unsigned* __restrict__ packed_sd, const int* __restrict__ eidq,
        const unsigned* __restrict__ bmeta,
        const _Float16* __restrict__ P_src, const _Float16* __restrict__ P_dst,
        const float* __restrict__ s_src, const float* __restrict__ s_dst,
        float* __restrict__ out, int BQ) {
    const int b = blockIdx.x & (NBKT - 1);
    const unsigned base = bmeta[b], cnt = bmeta[NBKT + b];
    const unsigned dbase = (unsigned)b * (unsigned)BQ;
    const unsigned jstr = gridDim.x >> 3;
    const int sub = threadIdx.x & 15;
    const int grp = threadIdx.x >> 4;            // 0..15 -> 32 edges/block
    for (unsigned j = blockIdx.x >> 3; j * 32 < cnt; j += jstr) {
        unsigned i0 = j * 32 + (unsigned)grp * 2;
        bool v0 = i0 < cnt, v1 = (i0 + 1) < cnt;
        unsigned ce0 = base + (v0 ? i0 : 0u);
        unsigned ce1 = base + (v1 ? i0 + 1 : (v0 ? i0 : 0u));
        unsigned p0 = packed_sd[ce0], p1 = packed_sd[ce1];
        int s0 = p0 & 0x1FFFF, d0 = (int)(dbase + (p0 >> 17));
        int s1 = p1 & 0x1FFFF, d1 = (int)(dbase + (p1 >> 17));
        const uint4 a0 = *(const uint4*)(P_src + (size_t)s0 * 128 + sub * 8);
        const uint4 b0 = *(const uint4*)(P_dst + (size_t)d0 * 128 + sub * 8);
        const uint4 a1 = *(const uint4*)(P_src + (size_t)s1 * 128 + sub * 8);
        const uint4 b1 = *(const uint4*)(P_dst + (size_t)d1 * 128 + sub * 8);
        float ssum = 0.f;
        if (sub < 2) {
            int s = sub ? s1 : s0;
            int d = sub ? d1 : d0;
            ssum = s_src[s] + s_dst[d];
        }
        float acc0 = 0.f, acc1 = 0.f;
        acc0 = __builtin_amdgcn_fdot2(__builtin_bit_cast(half2v, a0.x), __builtin_bit_cast(half2v, b0.x), acc0, false);
        acc0 = __builtin_amdgcn_fdot2(__builtin_bit_cast(half2v, a0.y), __builtin_bit_cast(half2v, b0.y), acc0, false);
        acc0 = __builtin_amdgcn_fdot2(__builtin_bit_cast(half2v, a0.z), __builtin_bit_cast(half2v, b0.z), acc0, false);
        acc0 = __builtin_amdgcn_fdot2(__builtin_bit_cast(half2v, a0.w), __builtin_bit_cast(half2v, b0.w), acc0, false);
        acc1 = __builtin_amdgcn_fdot2(__builtin_bit_cast(half2v, a1.x), __builtin_bit_cast(half2v, b1.x), acc1, false);
        acc1 = __builtin_amdgcn_fdot2(__builtin_bit_cast(half2v, a1.y), __builtin_bit_cast(half2v, b1.y), acc1, false);
        acc1 = __builtin_amdgcn_fdot2(__builtin_bit_cast(half2v, a1.z), __builtin_bit_cast(half2v, b1.z), acc1, false);
        acc1 = __builtin_amdgcn_fdot2(__builtin_bit_cast(half2v, a1.w), __builtin_bit_cast(half2v, b1.w), acc1, false);
#pragma unroll
        for (int off = 8; off; off >>= 1) {
            acc0 += __shfl_xor(acc0, off);
            acc1 += __shfl_xor(acc1, off);
        }
        if (sub == 0 && v0) {
            float v = fmaf(ALPHA_C, acc0, ssum);
            out[eidq[ce0]] = 1.0f / (1.0f + __expf(-v));
        }
        if (sub == 1 && v1) {
            float v = fmaf(ALPHA_C, acc1, ssum);
            out[eidq[ce1]] = 1.0f / (1.0f + __expf(-v));
        }
    }
}

// Fallback (unbucketed) edge kernel — identical to round-8/10 benched form.
__global__ __launch_bounds__(256) void k_edges(
        const int* __restrict__ eidx,
        const _Float16* __restrict__ P_src, const _Float16* __restrict__ P_dst,
        const float* __restrict__ s_src, const float* __restrict__ s_dst,
        float* __restrict__ out, int E) {
    const int sub = threadIdx.x & 15;
    const int grp = blockIdx.x * (blockDim.x >> 4) + (threadIdx.x >> 4);
    const int e0 = grp << 1;
    if (e0 >= E) return;
    const bool has1 = (e0 + 1) < E;
    int2 ss = *(const int2*)(eidx + e0);
    int2 dd = *(const int2*)(eidx + E + e0);
    const int s1 = has1 ? ss.y : ss.x, d1 = has1 ? dd.y : dd.x;
    const uint4 a0 = *(const uint4*)(P_src + (size_t)ss.x * 128 + sub * 8);
    const uint4 b0 = *(const uint4*)(P_dst + (size_t)dd.x * 128 + sub * 8);
    const uint4 a1 = *(const uint4*)(P_src + (size_t)s1 * 128 + sub * 8);
    const uint4 b1 = *(const uint4*)(P_dst + (size_t)d1 * 128 + sub * 8);
    float ssum = 0.f;
    if (sub < 2) {
        int s = sub ? s1 : ss.x;
        int d = sub ? d1 : dd.x;
        ssum = s_src[s] + s_dst[d];
    }
    float acc0 = 0.f, acc1 = 0.f;
    acc0 = __builtin_amdgcn_fdot2(__builtin_bit_cast(half2v, a0.x), __builtin_bit_cast(half2v, b0.x), acc0, false);
    acc0 = __builtin_amdgcn_fdot2(__builtin_bit_cast(half2v, a0.y), __builtin_bit_cast(half2v, b0.y), acc0, false);
    acc0 = __builtin_amdgcn_fdot2(__builtin_bit_cast(half2v, a0.z), __builtin_bit_cast(half2v, b0.z), acc0, false);
    acc0 = __builtin_amdgcn_fdot2(__builtin_bit_cast(half2v, a0.w), __builtin_bit_cast(half2v, b0.w), acc0, false);
    acc1 = __builtin_amdgcn_fdot2(__builtin_bit_cast(half2v, a1.x), __builtin_bit_cast(half2v, b1.x), acc1, false);
    acc1 = __builtin_amdgcn_fdot2(__builtin_bit_cast(half2v, a1.y), __builtin_bit_cast(half2v, b1.y), acc1, false);
    acc1 = __builtin_amdgcn_fdot2(__builtin_bit_cast(half2v, a1.z), __builtin_bit_cast(half2v, b1.z), acc1, false);
    acc1 = __builtin_amdgcn_fdot2(__builtin_bit_cast(half2v, a1.w), __builtin_bit_cast(half2v, b1.w), acc1, false);
#pragma unroll
    for (int off = 8; off; off >>= 1) {
        acc0 += __shfl_xor(acc0, off);
        acc1 += __shfl_xor(acc1, off);
    }
    if (sub < 2 && (sub == 0 || has1)) {
        float acc = sub ? acc1 : acc0;
        float v = fmaf(ALPHA_C, acc, ssum);
        out[e0 + sub] = 1.0f / (1.0f + __expf(-v));
    }
}

extern "C" void kernel_launch(void* const* d_in, const int* in_sizes, int n_in,
                              void* d_out, int out_size, void* d_ws, size_t ws_size,
                              hipStream_t stream) {
    const float* z_in   = (const float*)d_in[0];
    const float* z_out  = (const float*)d_in[1];
    const float* z_self = (const float*)d_in[2];
    const float* W_in   = (const float*)d_in[3];
    const float* b_in   = (const float*)d_in[4];
    const float* W_out  = (const float*)d_in[5];
    const float* b_out  = (const float*)d_in[6];
    const int*   eidx   = (const int*)d_in[7];

    const int N = in_sizes[2] / 64;   // z_self is [N, 64]
    const int E = in_sizes[7] / 2;    // edge_index is [2, E]

    // Histogram geometry: per-slice edge count < 65536 => u16-exact.
    const int Q = (N + NQUART - 1) / NQUART;
    const int Wd = (Q + 1) / 2;
    int S = (E + 49999) / 50000;
    if (S < 1) S = 1;
    int chunk = ((E + S - 1) / S + 3) & ~3;

    // Bucket geometry.
    const int BQ = (N + NBKT - 1) / NBKT;             // nodes per dst-bucket
    const int NWG = (E + SCH - 1) / SCH;              // scatter workgroups

    float* ws       = (float*)d_ws;
    float* deg_out  = ws;                             // N
    float* deg_in   = ws + (size_t)N;                 // N
    float* s_src    = ws + 2 * (size_t)N;             // N
    float* s_dst    = ws + 3 * (size_t)N;             // N
    _Float16* P_src = (_Float16*)(ws + 4 * (size_t)N);        // N*128 fp16
    _Float16* P_dst = P_src + (size_t)N * 128;                // N*128 fp16
    float* partials = (float*)(P_dst + (size_t)N * 128);      // 2*NPART
    float* inv_nrm  = partials + 2 * NPART;                   // 2
    unsigned* wgcnt = (unsigned*)(inv_nrm + 2);               // NWG*8
    unsigned* wgbase = wgcnt + (size_t)NWG * NBKT;            // NWG*8
    unsigned* bmeta  = wgbase + (size_t)NWG * NBKT;           // 16
    unsigned* packed_sd = bmeta + 16;                         // E
    int*      eidq      = (int*)(packed_sd + (size_t)E);      // E
    size_t need_bytes = (size_t)((char*)(eidq + (size_t)E) - (char*)d_ws);
    const bool bucketed = (ws_size >= need_bytes) && (N <= (1 << 17));
    // scr (hist scratch, ~12.8MB) aliases P_src region: dead before k_nodes.
    unsigned int* scr = (unsigned int*)P_src;

    dim3 hgrid(S, 2 * NQUART);
    k_hist<<<hgrid, 256, (size_t)Wd * 4, stream>>>(eidx, scr, N, E, Q, Wd, chunk);
    if (bucketed)
        k_bcnt<<<NWG, 256, 0, stream>>>(eidx, wgcnt, E, BQ);
    k_fold<<<NPART, 256, 0, stream>>>(scr, deg_out, deg_in, partials, N, Q, Wd, S);
    k_finish<<<1, 256, 0, stream>>>(partials, inv_nrm, wgcnt, wgbase, bmeta,
                                    bucketed ? NWG : 0);
    if (bucketed)
        k_scatter<<<NWG, 256, 0, stream>>>(eidx, wgbase, bmeta,
                                           packed_sd, eidq, E, BQ);
    k_nodes<<<(N + 63) / 64, 256, 0, stream>>>(z_in, z_out, z_self, W_in, b_in,
                                               W_out, b_out, deg_out, deg_in,
                                               inv_nrm, P_src, P_dst,
                                               s_src, s_dst, N);
    if (bucketed) {
        int blocks = ((E + 31) / 32 + 7) & ~7;        // multiple of 8
        k_edges2<<<blocks, 256, 0, stream>>>(packed_sd, eidq, bmeta,
                                             P_src, P_dst, s_src, s_dst,
                                             (float*)d_out, BQ);
    } else {
        int groups = (E + 1) / 2;
        int blocks = (groups + 15) / 16;
        k_edges<<<blocks, 256, 0, stream>>>(eidx, P_src, P_dst,
                                            s_src, s_dst, (float*)d_out, E);
    }
}

// Round 12
// 257.204 us; speedup vs baseline: 1.0765x; 1.0765x over previous
//
#include <hip/hip_runtime.h>
#include <hip/hip_fp16.h>
#include <math.h>

#define ALPHA_C 0.5f
#define BETA_C  0.5f
#define NPART   256
#define NQUART  4
#define NBKT    8
#define SCH     6250   // edges per bucket-count/scatter workgroup (NWG<=256)

typedef _Float16 half8 __attribute__((ext_vector_type(8)));
typedef _Float16 half2v __attribute__((ext_vector_type(2)));
typedef float f32x4 __attribute__((ext_vector_type(4)));

// XOR row-swizzle: spreads a column access across 8 LDS bank-groups.
__device__ __forceinline__ int swz(int row, int byteoff) {
    return byteoff ^ ((row & 7) << 4);
}

// Exact degree histogram with NO global atomics (round-4 design).
__global__ __launch_bounds__(256) void k_hist(
        const int* __restrict__ eidx, unsigned int* __restrict__ scr,
        int N, int E, int Q, int Wd, int chunk) {
    const int s = blockIdx.x;
    const int role = blockIdx.y;
    const int dir = role & 1;
    const int q = role >> 1;
    extern __shared__ unsigned int lds[];          // Wd words
    for (int w = threadIdx.x; w < Wd; w += blockDim.x) lds[w] = 0;
    __syncthreads();
    const int base = q * Q;
    const int hi = min(N - base, Q);
    const int* __restrict__ arr = eidx + (size_t)dir * E;
    const int start = s * chunk;
    const int end = min(E, start + chunk);
    const int4* __restrict__ a4 = (const int4*)arr;
    const int v1 = end >> 2;
    for (int v = (start >> 2) + threadIdx.x; v < v1; v += blockDim.x) {
        int4 x = a4[v];
        int l;
        l = x.x - base; if ((unsigned)l < (unsigned)hi) atomicAdd(&lds[l >> 1], 1u << ((l & 1) * 16));
        l = x.y - base; if ((unsigned)l < (unsigned)hi) atomicAdd(&lds[l >> 1], 1u << ((l & 1) * 16));
        l = x.z - base; if ((unsigned)l < (unsigned)hi) atomicAdd(&lds[l >> 1], 1u << ((l & 1) * 16));
        l = x.w - base; if ((unsigned)l < (unsigned)hi) atomicAdd(&lds[l >> 1], 1u << ((l & 1) * 16));
    }
    for (int i = (v1 << 2) + threadIdx.x; i < end; i += blockDim.x) {
        int l = arr[i] - base;
        if ((unsigned)l < (unsigned)hi) atomicAdd(&lds[l >> 1], 1u << ((l & 1) * 16));
    }
    __syncthreads();
    unsigned int* __restrict__ dst = scr + ((size_t)role * gridDim.x + s) * Wd;
    for (int w = threadIdx.x; w < Wd; w += blockDim.x) dst[w] = lds[w];
}

// Per-chunk dst-bucket counts (LDS atomics only, wave-ballot aggregated).
__global__ __launch_bounds__(256) void k_bcnt(
        const int* __restrict__ eidx, unsigned* __restrict__ wgcnt,
        int E, int BQ) {
    __shared__ unsigned cnt[NBKT];
    if (threadIdx.x < NBKT) cnt[threadIdx.x] = 0;
    __syncthreads();
    const int c0 = blockIdx.x * SCH;
    const int lim = min(E - c0, SCH);
    const int lane = threadIdx.x & 63;
    for (int it = 0; it * 256 < lim; ++it) {
        int i = it * 256 + threadIdx.x;
        unsigned bkt = NBKT;
        if (i < lim) bkt = (unsigned)eidx[E + c0 + i] / (unsigned)BQ;
#pragma unroll
        for (unsigned b = 0; b < NBKT; ++b) {
            unsigned long long m = __ballot(bkt == b);
            if (m && lane == (__ffsll((long long)m) - 1))
                atomicAdd(&cnt[b], (unsigned)__popcll(m));
        }
    }
    __syncthreads();
    if (threadIdx.x < NBKT) wgcnt[blockIdx.x * NBKT + threadIdx.x] = cnt[threadIdx.x];
}

// Fold slice histograms -> float degrees + sum-of-squares partials.
__global__ __launch_bounds__(256) void k_fold(
        const unsigned int* __restrict__ scr,
        float* __restrict__ deg_out, float* __restrict__ deg_in,
        float* __restrict__ partials, int N, int Q, int Wd, int S) {
    float so = 0.f, si = 0.f;
    for (int n = blockIdx.x * blockDim.x + threadIdx.x; n < N;
         n += gridDim.x * blockDim.x) {
        const int q = n / Q, l = n - q * Q;
        const int w = l >> 1, sh = (l & 1) * 16;
        const unsigned int* __restrict__ p0 = scr + ((size_t)(q * 2 + 0) * S) * Wd + w;
        const unsigned int* __restrict__ p1 = scr + ((size_t)(q * 2 + 1) * S) * Wd + w;
        unsigned int a = 0, b = 0;
        for (int s = 0; s < S; ++s) {
            a += (p0[(size_t)s * Wd] >> sh) & 0xFFFFu;
            b += (p1[(size_t)s * Wd] >> sh) & 0xFFFFu;
        }
        float fa = (float)a, fb = (float)b;
        deg_out[n] = fa;
        deg_in[n] = fb;
        so = fmaf(fa, fa, so);
        si = fmaf(fb, fb, si);
    }
#pragma unroll
    for (int off = 32; off; off >>= 1) {
        so += __shfl_xor(so, off);
        si += __shfl_xor(si, off);
    }
    __shared__ float sm[2][4];
    int lane = threadIdx.x & 63, w = threadIdx.x >> 6;
    if (lane == 0) { sm[0][w] = so; sm[1][w] = si; }
    __syncthreads();
    if (threadIdx.x == 0) {
        partials[blockIdx.x]         = sm[0][0] + sm[0][1] + sm[0][2] + sm[0][3];
        partials[NPART + blockIdx.x] = sm[1][0] + sm[1][1] + sm[1][2] + sm[1][3];
    }
}

// Norm finish + f16 W^T build + PARALLEL bucket scan (8 block-scans).
__global__ __launch_bounds__(256) void k_finish(
        const float* __restrict__ partials, float* __restrict__ inv_nrm,
        const float* __restrict__ W_in, const float* __restrict__ W_out,
        _Float16* __restrict__ w16i, _Float16* __restrict__ w16o,
        const unsigned* __restrict__ wgcnt, unsigned* __restrict__ wgbase,
        unsigned* __restrict__ bmeta, int NWG) {
    const int t = threadIdx.x;
    const int lane = t & 63, w = t >> 6;
    for (int i = t; i < 4096; i += 256) {
        int k = i >> 6, n = i & 63;
        w16o[n * 64 + k] = (_Float16)W_out[k * 64 + n];
        w16i[n * 64 + k] = (_Float16)W_in [k * 64 + n];
    }
    // ---- parallel exclusive scan per bucket over NWG (<=256) chunks ----
    __shared__ unsigned smw[4];
    __shared__ unsigned sb[NBKT];
    for (int b = 0; b < NBKT; ++b) {
        unsigned v = (t < NWG) ? wgcnt[t * NBKT + b] : 0u;
        unsigned x = v;
#pragma unroll
        for (int off = 1; off < 64; off <<= 1) {
            unsigned y = (unsigned)__shfl_up((int)x, off);
            if (lane >= off) x += y;
        }
        if (lane == 63) smw[w] = x;          // wave totals
        __syncthreads();
        unsigned wbase = 0;
        for (int ww = 0; ww < w; ++ww) wbase += smw[ww];
        if (t < NWG) wgbase[t * NBKT + b] = wbase + x - v;
        if (t == 255) sb[b] = wbase + x;     // bucket total
        __syncthreads();
    }
    // ---- norm finish ----
    float so = partials[t], si = partials[NPART + t];
#pragma unroll
    for (int off = 32; off; off >>= 1) {
        so += __shfl_xor(so, off);
        si += __shfl_xor(si, off);
    }
    __shared__ float sm[2][4];
    if (lane == 0) { sm[0][w] = so; sm[1][w] = si; }
    __syncthreads();
    if (t == 0) {
        float a = sm[0][0] + sm[0][1] + sm[0][2] + sm[0][3];
        float b = sm[1][0] + sm[1][1] + sm[1][2] + sm[1][3];
        inv_nrm[0] = (a > 0.f) ? rsqrtf(a) : 0.f;
        inv_nrm[1] = (b > 0.f) ? rsqrtf(b) : 0.f;
        if (NWG > 0) {
            unsigned acc = 0;
#pragma unroll
            for (int bb = 0; bb < NBKT; ++bb) {
                bmeta[bb] = acc;
                bmeta[NBKT + bb] = sb[bb];
                acc += sb[bb];
            }
        }
    }
}

// Direct scatter (no LDS staging; LDS = 8 cursors). Deterministic OUTPUT:
// each edge's out[eid] value is order-independent.
__global__ __launch_bounds__(256) void k_scatter(
        const int* __restrict__ eidx, const unsigned* __restrict__ wgbase,
        const unsigned* __restrict__ bmeta, unsigned* __restrict__ packed_sd,
        int* __restrict__ eidq, int E, int BQ) {
    __shared__ unsigned lcur[NBKT];
    const int c0 = blockIdx.x * SCH;
    const int lim = min(E - c0, SCH);
    const int tid = threadIdx.x, lane = tid & 63;
    if (tid < NBKT) lcur[tid] = bmeta[tid] + wgbase[blockIdx.x * NBKT + tid];
    __syncthreads();
    for (int it = 0; it * 256 < lim; ++it) {
        int i = it * 256 + tid;
        unsigned sd = 0, bkt = NBKT;
        if (i < lim) {
            unsigned s = (unsigned)eidx[c0 + i];
            unsigned d = (unsigned)eidx[E + c0 + i];
            bkt = d / (unsigned)BQ;
            sd = s | ((d - bkt * (unsigned)BQ) << 17);
        }
#pragma unroll
        for (unsigned b = 0; b < NBKT; ++b) {
            unsigned long long m = __ballot(bkt == b);
            if (!m) continue;
            int leader = __ffsll((long long)m) - 1;
            unsigned pbase = 0;
            if (lane == leader) pbase = atomicAdd(&lcur[b], (unsigned)__popcll(m));
            pbase = (unsigned)__shfl((int)pbase, leader);
            if (bkt == b) {
                unsigned pos = pbase + (unsigned)__popcll(m & ((1ULL << lane) - 1));
                packed_sd[pos] = sd;
                eidq[pos] = c0 + i;
            }
        }
    }
}

// MFMA node precompute, LDS-staged (round-7 benched form). W staged as pure
// 16B copies from the prebuilt f16 w16 arrays (no per-block cvt).
__global__ __launch_bounds__(256) void k_nodes(
        const float* __restrict__ z_in, const float* __restrict__ z_out,
        const float* __restrict__ z_self,
        const _Float16* __restrict__ w16i, const _Float16* __restrict__ w16o,
        const float* __restrict__ b_in, const float* __restrict__ b_out,
        const float* __restrict__ deg_out, const float* __restrict__ deg_in,
        const float* __restrict__ inv_nrm,
        _Float16* __restrict__ P_src, _Float16* __restrict__ P_dst,
        float* __restrict__ s_src, float* __restrict__ s_dst, int N) {
    __shared__ _Float16 smem[16384];                 // 32 KB
    char* lzo = (char*)smem;                         // [64][64] f16, 8 KB
    char* lzi = (char*)smem + 8192;
    char* lwo = (char*)smem + 16384;                 // W^T [n=64][k=64] f16
    char* lwi = (char*)smem + 24576;
    char* lps = (char*)smem;                         // [64][128] f16 (aliases)
    char* lpd = (char*)smem + 16384;

    const int tid = threadIdx.x;
    const int lane = tid & 63;
    const int wid = tid >> 6;
    const int r = lane & 15, g = lane >> 4;
    const int base = blockIdx.x * 64;
    const int wrow = wid * 16;

    // ---- phase 1: stage z tiles (cvt) and W^T (16B copies) into LDS ----
#pragma unroll
    for (int it = 0; it < 8; ++it) {
        int flat = it * 256 + tid;                   // [0, 2048)
        int row = flat >> 5;
        int c2 = (flat & 31) * 2;
        int grow = min(base + row, N - 1);
        const float* zr = z_out + (size_t)grow * 65;
        half2v ho = { (_Float16)zr[c2], (_Float16)zr[c2 + 1] };
        *(half2v*)(lzo + row * 128 + swz(row, c2 * 2)) = ho;
        const float* zr2 = z_in + (size_t)grow * 65;
        half2v hi = { (_Float16)zr2[c2], (_Float16)zr2[c2 + 1] };
        *(half2v*)(lzi + row * 128 + swz(row, c2 * 2)) = hi;
    }
#pragma unroll
    for (int it = 0; it < 2; ++it) {
        int flat = it * 256 + tid;                   // [0, 512) 16B chunks
        int n = flat >> 3;
        int c = flat & 7;
        *(half8*)(lwo + n * 128 + swz(n, c * 16)) = *(const half8*)(w16o + flat * 8);
        *(half8*)(lwi + n * 128 + swz(n, c * 16)) = *(const half8*)(w16i + flat * 8);
    }
    half8 bO[2], bI[2];
#pragma unroll
    for (int s = 0; s < 2; ++s)
#pragma unroll
        for (int j = 0; j < 8; ++j) {
            int k = 32 * s + 8 * g + j;
            bO[s][j] = (r == 0) ? (_Float16)b_out[k] : (_Float16)0.f;
            bI[s][j] = (r == 0) ? (_Float16)b_in [k] : (_Float16)0.f;
        }
    __syncthreads();

    // ---- phase 2: fragments from LDS + MFMA ----
    half8 AO[2], AI[2];
#pragma unroll
    for (int s = 0; s < 2; ++s) {
        int arow = wrow + r;
        int off = arow * 128 + swz(arow, s * 64 + g * 16);
        AO[s] = *(half8*)(lzo + off);
        AI[s] = *(half8*)(lzi + off);
    }
    f32x4 aO[4], aI[4], abO = (f32x4)0.f, abI = (f32x4)0.f;
#pragma unroll
    for (int t = 0; t < 4; ++t) { aO[t] = (f32x4)0.f; aI[t] = (f32x4)0.f; }
#pragma unroll
    for (int s = 0; s < 2; ++s) {
#pragma unroll
        for (int t = 0; t < 4; ++t) {
            int n = 16 * t + r;
            int off = n * 128 + swz(n, s * 64 + g * 16);
            half8 BO = *(half8*)(lwo + off);
            aO[t] = __builtin_amdgcn_mfma_f32_16x16x32_f16(AO[s], BO, aO[t], 0, 0, 0);
            half8 BI = *(half8*)(lwi + off);
            aI[t] = __builtin_amdgcn_mfma_f32_16x16x32_f16(AI[s], BI, aI[t], 0, 0, 0);
        }
        abO = __builtin_amdgcn_mfma_f32_16x16x32_f16(AO[s], bO[s], abO, 0, 0, 0);
        abI = __builtin_amdgcn_mfma_f32_16x16x32_f16(AI[s], bI[s], abI, 0, 0, 0);
    }
    __syncthreads();   // lz/lw dead; lp aliases them

    // ---- phase 3: results + z_self into swizzled LDS P-tiles ----
#pragma unroll
    for (int t = 0; t < 4; ++t)
#pragma unroll
        for (int rr = 0; rr < 4; ++rr) {
            int lrow = wrow + 4 * g + rr;
            int col2 = (16 * t + r) * 2;
            *(_Float16*)(lps + lrow * 256 + swz(lrow, col2)) = (_Float16)aO[t][rr];
            *(_Float16*)(lpd + lrow * 256 + swz(lrow, 128 + col2)) = (_Float16)aI[t][rr];
        }
#pragma unroll
    for (int it = 0; it < 8; ++it) {
        int flat = it * 256 + tid;
        int row = flat >> 5;
        int c2 = (flat & 31) * 2;
        int grow = min(base + row, N - 1);
        float2 v = *(const float2*)(z_self + (size_t)grow * 64 + c2);
        half2v h = { (_Float16)v.x, (_Float16)v.y };
        *(half2v*)(lps + row * 256 + swz(row, 128 + c2 * 2)) = h;   // P_src[,64:]
        *(half2v*)(lpd + row * 256 + swz(row, c2 * 2)) = h;         // P_dst[,:64]
    }
    if (r == 0) {
        const float i0 = inv_nrm[0], i1 = inv_nrm[1];
#pragma unroll
        for (int rr = 0; rr < 4; ++rr) {
            int m = base + wrow + 4 * g + rr;
            if (m < N) {
                s_src[m] = BETA_C * fmaf(deg_out[m], i0, z_out[(size_t)m * 65 + 64])
                         + ALPHA_C * abO[rr];
                s_dst[m] = BETA_C * fmaf(deg_in[m],  i1, z_in [(size_t)m * 65 + 64])
                         + ALPHA_C * abI[rr];
            }
        }
    }
    __syncthreads();

    // ---- phase 4: coalesced 16B/lane flush to global ----
#pragma unroll
    for (int it = 0; it < 4; ++it) {
        int lrow = it * 16 + (tid >> 4);
        int seg = tid & 15;
        int m = base + lrow;
        if (m < N) {
            half8 v = *(half8*)(lps + lrow * 256 + swz(lrow, seg * 16));
            *(half8*)(P_src + (size_t)m * 128 + seg * 8) = v;
            half8 v2 = *(half8*)(lpd + lrow * 256 + swz(lrow, seg * 16));
            *(half8*)(P_dst + (size_t)m * 128 + seg * 8) = v2;
        }
    }
}

// Bucketed edge kernel: bucket = blockIdx%8 -> XCD-pinned dst slice.
__global__ __launch_bounds__(256) void k_edges2(
        const unsigned* __restrict__ packed_sd, const int* __restrict__ eidq,
        const unsigned* __restrict__ bmeta,
        const _Float16* __restrict__ P_src, const _Float16* __restrict__ P_dst,
        const float* __restrict__ s_src, const float* __restrict__ s_dst,
        float* __restrict__ out, int BQ) {
    const int b = blockIdx.x & (NBKT - 1);
    const unsigned base = bmeta[b], cnt = bmeta[NBKT + b];
    const unsigned dbase = (unsigned)b * (unsigned)BQ;
    const unsigned jstr = gridDim.x >> 3;
    const int sub = threadIdx.x & 15;
    const int grp = threadIdx.x >> 4;            // 0..15 -> 32 edges/block
    for (unsigned j = blockIdx.x >> 3; j * 32 < cnt; j += jstr) {
        unsigned i0 = j * 32 + (unsigned)grp * 2;
        bool v0 = i0 < cnt, v1 = (i0 + 1) < cnt;
        unsigned ce0 = base + (v0 ? i0 : 0u);
        unsigned ce1 = base + (v1 ? i0 + 1 : (v0 ? i0 : 0u));
        unsigned p0 = packed_sd[ce0], p1 = packed_sd[ce1];
        int s0 = p0 & 0x1FFFF, d0 = (int)(dbase + (p0 >> 17));
        int s1 = p1 & 0x1FFFF, d1 = (int)(dbase + (p1 >> 17));
        const uint4 a0 = *(const uint4*)(P_src + (size_t)s0 * 128 + sub * 8);
        const uint4 b0 = *(const uint4*)(P_dst + (size_t)d0 * 128 + sub * 8);
        const uint4 a1 = *(const uint4*)(P_src + (size_t)s1 * 128 + sub * 8);
        const uint4 b1 = *(const uint4*)(P_dst + (size_t)d1 * 128 + sub * 8);
        float ssum = 0.f;
        if (sub < 2) {
            int s = sub ? s1 : s0;
            int d = sub ? d1 : d0;
            ssum = s_src[s] + s_dst[d];
        }
        float acc0 = 0.f, acc1 = 0.f;
        acc0 = __builtin_amdgcn_fdot2(__builtin_bit_cast(half2v, a0.x), __builtin_bit_cast(half2v, b0.x), acc0, false);
        acc0 = __builtin_amdgcn_fdot2(__builtin_bit_cast(half2v, a0.y), __builtin_bit_cast(half2v, b0.y), acc0, false);
        acc0 = __builtin_amdgcn_fdot2(__builtin_bit_cast(half2v, a0.z), __builtin_bit_cast(half2v, b0.z), acc0, false);
        acc0 = __builtin_amdgcn_fdot2(__builtin_bit_cast(half2v, a0.w), __builtin_bit_cast(half2v, b0.w), acc0, false);
        acc1 = __builtin_amdgcn_fdot2(__builtin_bit_cast(half2v, a1.x), __builtin_bit_cast(half2v, b1.x), acc1, false);
        acc1 = __builtin_amdgcn_fdot2(__builtin_bit_cast(half2v, a1.y), __builtin_bit_cast(half2v, b1.y), acc1, false);
        acc1 = __builtin_amdgcn_fdot2(__builtin_bit_cast(half2v, a1.z), __builtin_bit_cast(half2v, b1.z), acc1, false);
        acc1 = __builtin_amdgcn_fdot2(__builtin_bit_cast(half2v, a1.w), __builtin_bit_cast(half2v, b1.w), acc1, false);
#pragma unroll
        for (int off = 8; off; off >>= 1) {
            acc0 += __shfl_xor(acc0, off);
            acc1 += __shfl_xor(acc1, off);
        }
        if (sub == 0 && v0) {
            float v = fmaf(ALPHA_C, acc0, ssum);
            out[eidq[ce0]] = 1.0f / (1.0f + __expf(-v));
        }
        if (sub == 1 && v1) {
            float v = fmaf(ALPHA_C, acc1, ssum);
            out[eidq[ce1]] = 1.0f / (1.0f + __expf(-v));
        }
    }
}

// Fallback (unbucketed) edge kernel.
__global__ __launch_bounds__(256) void k_edges(
        const int* __restrict__ eidx,
        const _Float16* __restrict__ P_src, const _Float16* __restrict__ P_dst,
        const float* __restrict__ s_src, const float* __restrict__ s_dst,
        float* __restrict__ out, int E) {
    const int sub = threadIdx.x & 15;
    const int grp = blockIdx.x * (blockDim.x >> 4) + (threadIdx.x >> 4);
    const int e0 = grp << 1;
    if (e0 >= E) return;
    const bool has1 = (e0 + 1) < E;
    int2 ss = *(const int2*)(eidx + e0);
    int2 dd = *(const int2*)(eidx + E + e0);
    const int s1 = has1 ? ss.y : ss.x, d1 = has1 ? dd.y : dd.x;
    const uint4 a0 = *(const uint4*)(P_src + (size_t)ss.x * 128 + sub * 8);
    const uint4 b0 = *(const uint4*)(P_dst + (size_t)dd.x * 128 + sub * 8);
    const uint4 a1 = *(const uint4*)(P_src + (size_t)s1 * 128 + sub * 8);
    const uint4 b1 = *(const uint4*)(P_dst + (size_t)d1 * 128 + sub * 8);
    float ssum = 0.f;
    if (sub < 2) {
        int s = sub ? s1 : ss.x;
        int d = sub ? d1 : dd.x;
        ssum = s_src[s] + s_dst[d];
    }
    float acc0 = 0.f, acc1 = 0.f;
    acc0 = __builtin_amdgcn_fdot2(__builtin_bit_cast(half2v, a0.x), __builtin_bit_cast(half2v, b0.x), acc0, false);
    acc0 = __builtin_amdgcn_fdot2(__builtin_bit_cast(half2v, a0.y), __builtin_bit_cast(half2v, b0.y), acc0, false);
    acc0 = __builtin_amdgcn_fdot2(__builtin_bit_cast(half2v, a0.z), __builtin_bit_cast(half2v, b0.z), acc0, false);
    acc0 = __builtin_amdgcn_fdot2(__builtin_bit_cast(half2v, a0.w), __builtin_bit_cast(half2v, b0.w), acc0, false);
    acc1 = __builtin_amdgcn_fdot2(__builtin_bit_cast(half2v, a1.x), __builtin_bit_cast(half2v, b1.x), acc1, false);
    acc1 = __builtin_amdgcn_fdot2(__builtin_bit_cast(half2v, a1.y), __builtin_bit_cast(half2v, b1.y), acc1, false);
    acc1 = __builtin_amdgcn_fdot2(__builtin_bit_cast(half2v, a1.z), __builtin_bit_cast(half2v, b1.z), acc1, false);
    acc1 = __builtin_amdgcn_fdot2(__builtin_bit_cast(half2v, a1.w), __builtin_bit_cast(half2v, b1.w), acc1, false);
#pragma unroll
    for (int off = 8; off; off >>= 1) {
        acc0 += __shfl_xor(acc0, off);
        acc1 += __shfl_xor(acc1, off);
    }
    if (sub < 2 && (sub == 0 || has1)) {
        float acc = sub ? acc1 : acc0;
        float v = fmaf(ALPHA_C, acc, ssum);
        out[e0 + sub] = 1.0f / (1.0f + __expf(-v));
    }
}

extern "C" void kernel_launch(void* const* d_in, const int* in_sizes, int n_in,
                              void* d_out, int out_size, void* d_ws, size_t ws_size,
                              hipStream_t stream) {
    const float* z_in   = (const float*)d_in[0];
    const float* z_out  = (const float*)d_in[1];
    const float* z_self = (const float*)d_in[2];
    const float* W_in   = (const float*)d_in[3];
    const float* b_in   = (const float*)d_in[4];
    const float* W_out  = (const float*)d_in[5];
    const float* b_out  = (const float*)d_in[6];
    const int*   eidx   = (const int*)d_in[7];

    const int N = in_sizes[2] / 64;   // z_self is [N, 64]
    const int E = in_sizes[7] / 2;    // edge_index is [2, E]

    // Histogram geometry: per-slice edge count < 65536 => u16-exact.
    const int Q = (N + NQUART - 1) / NQUART;
    const int Wd = (Q + 1) / 2;
    int S = (E + 49999) / 50000;
    if (S < 1) S = 1;
    int chunk = ((E + S - 1) / S + 3) & ~3;

    // Bucket geometry.
    const int BQ = (N + NBKT - 1) / NBKT;             // nodes per dst-bucket
    const int NWG = (E + SCH - 1) / SCH;              // count/scatter WGs

    float* ws       = (float*)d_ws;
    float* deg_out  = ws;                             // N
    float* deg_in   = ws + (size_t)N;                 // N
    float* s_src    = ws + 2 * (size_t)N;             // N
    float* s_dst    = ws + 3 * (size_t)N;             // N
    _Float16* P_src = (_Float16*)(ws + 4 * (size_t)N);        // N*128 fp16
    _Float16* P_dst = P_src + (size_t)N * 128;                // N*128 fp16
    float* partials = (float*)(P_dst + (size_t)N * 128);      // 2*NPART
    float* inv_nrm  = partials + 2 * NPART;                   // 2
    _Float16* w16o  = (_Float16*)(inv_nrm + 2 + 12);          // 4096 f16 (16B-aligned)
    _Float16* w16i  = w16o + 4096;                            // 4096 f16
    unsigned* wgcnt = (unsigned*)(w16i + 4096);               // NWG*8
    unsigned* wgbase = wgcnt + (size_t)NWG * NBKT;            // NWG*8
    unsigned* bmeta  = wgbase + (size_t)NWG * NBKT;           // 16
    unsigned* packed_sd = bmeta + 16;                         // E
    int*      eidq      = (int*)(packed_sd + (size_t)E);      // E
    size_t need_bytes = (size_t)((char*)(eidq + (size_t)E) - (char*)d_ws);
    const bool bucketed = (ws_size >= need_bytes) && (N <= (1 << 17))
                          && (NWG <= 256);
    // scr (hist scratch, ~12.8MB) aliases P_src region: dead before k_nodes.
    unsigned int* scr = (unsigned int*)P_src;

    dim3 hgrid(S, 2 * NQUART);
    k_hist<<<hgrid, 256, (size_t)Wd * 4, stream>>>(eidx, scr, N, E, Q, Wd, chunk);
    if (bucketed)
        k_bcnt<<<NWG, 256, 0, stream>>>(eidx, wgcnt, E, BQ);
    k_fold<<<NPART, 256, 0, stream>>>(scr, deg_out, deg_in, partials, N, Q, Wd, S);
    k_finish<<<1, 256, 0, stream>>>(partials, inv_nrm, W_in, W_out, w16i, w16o,
                                    wgcnt, wgbase, bmeta, bucketed ? NWG : 0);
    if (bucketed)
        k_scatter<<<NWG, 256, 0, stream>>>(eidx, wgbase, bmeta,
                                           packed_sd, eidq, E, BQ);
    k_nodes<<<(N + 63) / 64, 256, 0, stream>>>(z_in, z_out, z_self, w16i, w16o,
                                               b_in, b_out, deg_out, deg_in,
                                               inv_nrm, P_src, P_dst,
                                               s_src, s_dst, N);
    if (bucketed) {
        int blocks = ((E + 31) / 32 + 7) & ~7;        // multiple of 8
        k_edges2<<<blocks, 256, 0, stream>>>(packed_sd, eidq, bmeta,
                                             P_src, P_dst, s_src, s_dst,
                                             (float*)d_out, BQ);
    } else {
        int groups = (E + 1) / 2;
        int blocks = (groups + 15) / 16;
        k_edges<<<blocks, 256, 0, stream>>>(eidx, P_src, P_dst,
                                            s_src, s_dst, (float*)d_out, E);
    }
}

// Round 13
// 204.258 us; speedup vs baseline: 1.3555x; 1.2592x over previous
//
#include <hip/hip_runtime.h>
#include <hip/hip_fp16.h>
#include <math.h>

#define ALPHA_C 0.5f
#define BETA_C  0.5f
#define NPART   256
#define NQUART  4

typedef _Float16 half8 __attribute__((ext_vector_type(8)));
typedef _Float16 half2v __attribute__((ext_vector_type(2)));
typedef float f32x4 __attribute__((ext_vector_type(4)));

// XOR row-swizzle: spreads a column access across 8 LDS bank-groups.
__device__ __forceinline__ int swz(int row, int byteoff) {
    return byteoff ^ ((row & 7) << 4);
}

// Exact degree histogram with NO global atomics (round-4 design).
__global__ __launch_bounds__(256) void k_hist(
        const int* __restrict__ eidx, unsigned int* __restrict__ scr,
        int N, int E, int Q, int Wd, int chunk) {
    const int s = blockIdx.x;
    const int role = blockIdx.y;
    const int dir = role & 1;
    const int q = role >> 1;
    extern __shared__ unsigned int lds[];          // Wd words
    for (int w = threadIdx.x; w < Wd; w += blockDim.x) lds[w] = 0;
    __syncthreads();
    const int base = q * Q;
    const int hi = min(N - base, Q);
    const int* __restrict__ arr = eidx + (size_t)dir * E;
    const int start = s * chunk;
    const int end = min(E, start + chunk);
    const int4* __restrict__ a4 = (const int4*)arr;
    const int v1 = end >> 2;
    for (int v = (start >> 2) + threadIdx.x; v < v1; v += blockDim.x) {
        int4 x = a4[v];
        int l;
        l = x.x - base; if ((unsigned)l < (unsigned)hi) atomicAdd(&lds[l >> 1], 1u << ((l & 1) * 16));
        l = x.y - base; if ((unsigned)l < (unsigned)hi) atomicAdd(&lds[l >> 1], 1u << ((l & 1) * 16));
        l = x.z - base; if ((unsigned)l < (unsigned)hi) atomicAdd(&lds[l >> 1], 1u << ((l & 1) * 16));
        l = x.w - base; if ((unsigned)l < (unsigned)hi) atomicAdd(&lds[l >> 1], 1u << ((l & 1) * 16));
    }
    for (int i = (v1 << 2) + threadIdx.x; i < end; i += blockDim.x) {
        int l = arr[i] - base;
        if ((unsigned)l < (unsigned)hi) atomicAdd(&lds[l >> 1], 1u << ((l & 1) * 16));
    }
    __syncthreads();
    unsigned int* __restrict__ dst = scr + ((size_t)role * gridDim.x + s) * Wd;
    for (int w = threadIdx.x; w < Wd; w += blockDim.x) dst[w] = lds[w];
}

// Fold slice histograms -> float degrees + sum-of-squares partials.
__global__ __launch_bounds__(256) void k_fold(
        const unsigned int* __restrict__ scr,
        float* __restrict__ deg_out, float* __restrict__ deg_in,
        float* __restrict__ partials, int N, int Q, int Wd, int S) {
    float so = 0.f, si = 0.f;
    for (int n = blockIdx.x * blockDim.x + threadIdx.x; n < N;
         n += gridDim.x * blockDim.x) {
        const int q = n / Q, l = n - q * Q;
        const int w = l >> 1, sh = (l & 1) * 16;
        const unsigned int* __restrict__ p0 = scr + ((size_t)(q * 2 + 0) * S) * Wd + w;
        const unsigned int* __restrict__ p1 = scr + ((size_t)(q * 2 + 1) * S) * Wd + w;
        unsigned int a = 0, b = 0;
        for (int s = 0; s < S; ++s) {
            a += (p0[(size_t)s * Wd] >> sh) & 0xFFFFu;
            b += (p1[(size_t)s * Wd] >> sh) & 0xFFFFu;
        }
        float fa = (float)a, fb = (float)b;
        deg_out[n] = fa;
        deg_in[n] = fb;
        so = fmaf(fa, fa, so);
        si = fmaf(fb, fb, si);
    }
#pragma unroll
    for (int off = 32; off; off >>= 1) {
        so += __shfl_xor(so, off);
        si += __shfl_xor(si, off);
    }
    __shared__ float sm[2][4];
    int lane = threadIdx.x & 63, w = threadIdx.x >> 6;
    if (lane == 0) { sm[0][w] = so; sm[1][w] = si; }
    __syncthreads();
    if (threadIdx.x == 0) {
        partials[blockIdx.x]         = sm[0][0] + sm[0][1] + sm[0][2] + sm[0][3];
        partials[NPART + blockIdx.x] = sm[1][0] + sm[1][1] + sm[1][2] + sm[1][3];
    }
}

// Norm finish + f16 W^T build.
__global__ __launch_bounds__(256) void k_finish(
        const float* __restrict__ partials, float* __restrict__ inv_nrm,
        const float* __restrict__ W_in, const float* __restrict__ W_out,
        _Float16* __restrict__ w16i, _Float16* __restrict__ w16o) {
    int t = threadIdx.x;
    for (int i = t; i < 4096; i += 256) {
        int k = i >> 6, n = i & 63;
        w16o[n * 64 + k] = (_Float16)W_out[k * 64 + n];
        w16i[n * 64 + k] = (_Float16)W_in [k * 64 + n];
    }
    float so = partials[t], si = partials[NPART + t];
#pragma unroll
    for (int off = 32; off; off >>= 1) {
        so += __shfl_xor(so, off);
        si += __shfl_xor(si, off);
    }
    __shared__ float sm[2][4];
    int lane = t & 63, w = t >> 6;
    if (lane == 0) { sm[0][w] = so; sm[1][w] = si; }
    __syncthreads();
    if (t == 0) {
        float a = sm[0][0] + sm[0][1] + sm[0][2] + sm[0][3];
        float b = sm[1][0] + sm[1][1] + sm[1][2] + sm[1][3];
        inv_nrm[0] = (a > 0.f) ? rsqrtf(a) : 0.f;
        inv_nrm[1] = (b > 0.f) ? rsqrtf(b) : 0.f;
    }
}

// MFMA node precompute, LDS-staged (round-7 form) with W staged as pure 16B
// copies from prebuilt f16 w16 arrays (r12-verified). Fragment maps:
//   A[m][k]: m = lane&15, k = 32*s + 8*(lane>>4) + j
//   B[k][n]: n = lane&15, k = 32*s + 8*(lane>>4) + j  (w16 = W^T [n][k])
//   D[m][n]: n = lane&15, m = 4*(lane>>4) + reg
__global__ __launch_bounds__(256) void k_nodes(
        const float* __restrict__ z_in, const float* __restrict__ z_out,
        const float* __restrict__ z_self,
        const _Float16* __restrict__ w16i, const _Float16* __restrict__ w16o,
        const float* __restrict__ b_in, const float* __restrict__ b_out,
        const float* __restrict__ deg_out, const float* __restrict__ deg_in,
        const float* __restrict__ inv_nrm,
        _Float16* __restrict__ P_src, _Float16* __restrict__ P_dst,
        float* __restrict__ s_src, float* __restrict__ s_dst, int N) {
    __shared__ _Float16 smem[16384];                 // 32 KB
    char* lzo = (char*)smem;                         // [64][64] f16, 8 KB
    char* lzi = (char*)smem + 8192;
    char* lwo = (char*)smem + 16384;                 // W^T [n=64][k=64] f16
    char* lwi = (char*)smem + 24576;
    char* lps = (char*)smem;                         // [64][128] f16 (aliases)
    char* lpd = (char*)smem + 16384;

    const int tid = threadIdx.x;
    const int lane = tid & 63;
    const int wid = tid >> 6;
    const int r = lane & 15, g = lane >> 4;
    const int base = blockIdx.x * 64;
    const int wrow = wid * 16;

    // ---- phase 1: stage z tiles (cvt) and W^T (16B copies) into LDS ----
#pragma unroll
    for (int it = 0; it < 8; ++it) {
        int flat = it * 256 + tid;                   // [0, 2048)
        int row = flat >> 5;
        int c2 = (flat & 31) * 2;
        int grow = min(base + row, N - 1);
        const float* zr = z_out + (size_t)grow * 65;
        half2v ho = { (_Float16)zr[c2], (_Float16)zr[c2 + 1] };
        *(half2v*)(lzo + row * 128 + swz(row, c2 * 2)) = ho;
        const float* zr2 = z_in + (size_t)grow * 65;
        half2v hi = { (_Float16)zr2[c2], (_Float16)zr2[c2 + 1] };
        *(half2v*)(lzi + row * 128 + swz(row, c2 * 2)) = hi;
    }
#pragma unroll
    for (int it = 0; it < 2; ++it) {
        int flat = it * 256 + tid;                   // [0, 512) 16B chunks
        int n = flat >> 3;
        int c = flat & 7;
        *(half8*)(lwo + n * 128 + swz(n, c * 16)) = *(const half8*)(w16o + flat * 8);
        *(half8*)(lwi + n * 128 + swz(n, c * 16)) = *(const half8*)(w16i + flat * 8);
    }
    half8 bO[2], bI[2];
#pragma unroll
    for (int s = 0; s < 2; ++s)
#pragma unroll
        for (int j = 0; j < 8; ++j) {
            int k = 32 * s + 8 * g + j;
            bO[s][j] = (r == 0) ? (_Float16)b_out[k] : (_Float16)0.f;
            bI[s][j] = (r == 0) ? (_Float16)b_in [k] : (_Float16)0.f;
        }
    __syncthreads();

    // ---- phase 2: fragments from LDS + MFMA ----
    half8 AO[2], AI[2];
#pragma unroll
    for (int s = 0; s < 2; ++s) {
        int arow = wrow + r;
        int off = arow * 128 + swz(arow, s * 64 + g * 16);
        AO[s] = *(half8*)(lzo + off);
        AI[s] = *(half8*)(lzi + off);
    }
    f32x4 aO[4], aI[4], abO = (f32x4)0.f, abI = (f32x4)0.f;
#pragma unroll
    for (int t = 0; t < 4; ++t) { aO[t] = (f32x4)0.f; aI[t] = (f32x4)0.f; }
#pragma unroll
    for (int s = 0; s < 2; ++s) {
#pragma unroll
        for (int t = 0; t < 4; ++t) {
            int n = 16 * t + r;
            int off = n * 128 + swz(n, s * 64 + g * 16);
            half8 BO = *(half8*)(lwo + off);
            aO[t] = __builtin_amdgcn_mfma_f32_16x16x32_f16(AO[s], BO, aO[t], 0, 0, 0);
            half8 BI = *(half8*)(lwi + off);
            aI[t] = __builtin_amdgcn_mfma_f32_16x16x32_f16(AI[s], BI, aI[t], 0, 0, 0);
        }
        abO = __builtin_amdgcn_mfma_f32_16x16x32_f16(AO[s], bO[s], abO, 0, 0, 0);
        abI = __builtin_amdgcn_mfma_f32_16x16x32_f16(AI[s], bI[s], abI, 0, 0, 0);
    }
    __syncthreads();   // lz/lw dead; lp aliases them

    // ---- phase 3: results + z_self into swizzled LDS P-tiles ----
#pragma unroll
    for (int t = 0; t < 4; ++t)
#pragma unroll
        for (int rr = 0; rr < 4; ++rr) {
            int lrow = wrow + 4 * g + rr;
            int col2 = (16 * t + r) * 2;
            *(_Float16*)(lps + lrow * 256 + swz(lrow, col2)) = (_Float16)aO[t][rr];
            *(_Float16*)(lpd + lrow * 256 + swz(lrow, 128 + col2)) = (_Float16)aI[t][rr];
        }
#pragma unroll
    for (int it = 0; it < 8; ++it) {
        int flat = it * 256 + tid;
        int row = flat >> 5;
        int c2 = (flat & 31) * 2;
        int grow = min(base + row, N - 1);
        float2 v = *(const float2*)(z_self + (size_t)grow * 64 + c2);
        half2v h = { (_Float16)v.x, (_Float16)v.y };
        *(half2v*)(lps + row * 256 + swz(row, 128 + c2 * 2)) = h;   // P_src[,64:]
        *(half2v*)(lpd + row * 256 + swz(row, c2 * 2)) = h;         // P_dst[,:64]
    }
    if (r == 0) {
        const float i0 = inv_nrm[0], i1 = inv_nrm[1];
#pragma unroll
        for (int rr = 0; rr < 4; ++rr) {
            int m = base + wrow + 4 * g + rr;
            if (m < N) {
                s_src[m] = BETA_C * fmaf(deg_out[m], i0, z_out[(size_t)m * 65 + 64])
                         + ALPHA_C * abO[rr];
                s_dst[m] = BETA_C * fmaf(deg_in[m],  i1, z_in [(size_t)m * 65 + 64])
                         + ALPHA_C * abI[rr];
            }
        }
    }
    __syncthreads();

    // ---- phase 4: coalesced 16B/lane flush to global ----
#pragma unroll
    for (int it = 0; it < 4; ++it) {
        int lrow = it * 16 + (tid >> 4);
        int seg = tid & 15;
        int m = base + lrow;
        if (m < N) {
            half8 v = *(half8*)(lps + lrow * 256 + swz(lrow, seg * 16));
            *(half8*)(P_src + (size_t)m * 128 + seg * 8) = v;
            half8 v2 = *(half8*)(lpd + lrow * 256 + swz(lrow, seg * 16));
            *(half8*)(P_dst + (size_t)m * 128 + seg * 8) = v2;
        }
    }
}

// Per-edge: 16 lanes per FOUR edges (8x 16B gathers in flight per lane).
__global__ __launch_bounds__(256) void k_edges(
        const int* __restrict__ eidx,
        const _Float16* __restrict__ P_src, const _Float16* __restrict__ P_dst,
        const float* __restrict__ s_src, const float* __restrict__ s_dst,
        float* __restrict__ out, int E) {
    const int sub = threadIdx.x & 15;
    const int grp = blockIdx.x * 16 + (threadIdx.x >> 4);
    const int e0 = grp << 2;
    if (e0 >= E) return;
    int se0 = eidx[min(e0 + 0, E - 1)], de0 = eidx[E + min(e0 + 0, E - 1)];
    int se1 = eidx[min(e0 + 1, E - 1)], de1 = eidx[E + min(e0 + 1, E - 1)];
    int se2 = eidx[min(e0 + 2, E - 1)], de2 = eidx[E + min(e0 + 2, E - 1)];
    int se3 = eidx[min(e0 + 3, E - 1)], de3 = eidx[E + min(e0 + 3, E - 1)];
    const uint4 a0 = *(const uint4*)(P_src + (size_t)se0 * 128 + sub * 8);
    const uint4 b0 = *(const uint4*)(P_dst + (size_t)de0 * 128 + sub * 8);
    const uint4 a1 = *(const uint4*)(P_src + (size_t)se1 * 128 + sub * 8);
    const uint4 b1 = *(const uint4*)(P_dst + (size_t)de1 * 128 + sub * 8);
    const uint4 a2 = *(const uint4*)(P_src + (size_t)se2 * 128 + sub * 8);
    const uint4 b2 = *(const uint4*)(P_dst + (size_t)de2 * 128 + sub * 8);
    const uint4 a3 = *(const uint4*)(P_src + (size_t)se3 * 128 + sub * 8);
    const uint4 b3 = *(const uint4*)(P_dst + (size_t)de3 * 128 + sub * 8);
    float ssum = 0.f;
    if (sub < 4) {
        int s = (sub == 0) ? se0 : (sub == 1) ? se1 : (sub == 2) ? se2 : se3;
        int d = (sub == 0) ? de0 : (sub == 1) ? de1 : (sub == 2) ? de2 : de3;
        ssum = s_src[s] + s_dst[d];
    }
#define DOT8(acc, A, B)                                                          \
    acc = __builtin_amdgcn_fdot2(__builtin_bit_cast(half2v, A.x),                \
                                 __builtin_bit_cast(half2v, B.x), acc, false);   \
    acc = __builtin_amdgcn_fdot2(__builtin_bit_cast(half2v, A.y),                \
                                 __builtin_bit_cast(half2v, B.y), acc, false);   \
    acc = __builtin_amdgcn_fdot2(__builtin_bit_cast(half2v, A.z),                \
                                 __builtin_bit_cast(half2v, B.z), acc, false);   \
    acc = __builtin_amdgcn_fdot2(__builtin_bit_cast(half2v, A.w),                \
                                 __builtin_bit_cast(half2v, B.w), acc, false)
    float acc0 = 0.f, acc1 = 0.f, acc2 = 0.f, acc3 = 0.f;
    DOT8(acc0, a0, b0);
    DOT8(acc1, a1, b1);
    DOT8(acc2, a2, b2);
    DOT8(acc3, a3, b3);
#undef DOT8
#pragma unroll
    for (int off = 8; off; off >>= 1) {
        acc0 += __shfl_xor(acc0, off);
        acc1 += __shfl_xor(acc1, off);
        acc2 += __shfl_xor(acc2, off);
        acc3 += __shfl_xor(acc3, off);
    }
    if (sub < 4 && e0 + sub < E) {
        float acc = (sub == 0) ? acc0 : (sub == 1) ? acc1 : (sub == 2) ? acc2 : acc3;
        float v = fmaf(ALPHA_C, acc, ssum);
        out[e0 + sub] = 1.0f / (1.0f + __expf(-v));
    }
}

extern "C" void kernel_launch(void* const* d_in, const int* in_sizes, int n_in,
                              void* d_out, int out_size, void* d_ws, size_t ws_size,
                              hipStream_t stream) {
    const float* z_in   = (const float*)d_in[0];
    const float* z_out  = (const float*)d_in[1];
    const float* z_self = (const float*)d_in[2];
    const float* W_in   = (const float*)d_in[3];
    const float* b_in   = (const float*)d_in[4];
    const float* W_out  = (const float*)d_in[5];
    const float* b_out  = (const float*)d_in[6];
    const int*   eidx   = (const int*)d_in[7];

    const int N = in_sizes[2] / 64;   // z_self is [N, 64]
    const int E = in_sizes[7] / 2;    // edge_index is [2, E]

    // Histogram geometry: per-slice edge count < 65536 => u16-exact.
    const int Q = (N + NQUART - 1) / NQUART;
    const int Wd = (Q + 1) / 2;
    int S = (E + 49999) / 50000;
    if (S < 1) S = 1;
    int chunk = ((E + S - 1) / S + 3) & ~3;

    float* ws       = (float*)d_ws;
    float* deg_out  = ws;                             // N
    float* deg_in   = ws + (size_t)N;                 // N
    float* s_src    = ws + 2 * (size_t)N;             // N
    float* s_dst    = ws + 3 * (size_t)N;             // N
    _Float16* P_src = (_Float16*)(ws + 4 * (size_t)N);        // N*128 fp16
    _Float16* P_dst = P_src + (size_t)N * 128;                // N*128 fp16
    float* partials = (float*)(P_dst + (size_t)N * 128);      // 2*NPART
    float* inv_nrm  = partials + 2 * NPART;                   // 2
    _Float16* w16o  = (_Float16*)(inv_nrm + 2 + 12);          // 4096 f16 (16B-aligned)
    _Float16* w16i  = w16o + 4096;                            // 4096 f16
    // scr (hist scratch, ~12.8MB) aliases P_src region: dead before k_nodes.
    unsigned int* scr = (unsigned int*)P_src;

    dim3 hgrid(S, 2 * NQUART);
    k_hist<<<hgrid, 256, (size_t)Wd * 4, stream>>>(eidx, scr, N, E, Q, Wd, chunk);
    k_fold<<<NPART, 256, 0, stream>>>(scr, deg_out, deg_in, partials, N, Q, Wd, S);
    k_finish<<<1, 256, 0, stream>>>(partials, inv_nrm, W_in, W_out, w16i, w16o);
    k_nodes<<<(N + 63) / 64, 256, 0, stream>>>(z_in, z_out, z_self, w16i, w16o,
                                               b_in, b_out, deg_out, deg_in,
                                               inv_nrm, P_src, P_dst,
                                               s_src, s_dst, N);
    {
        int blocks = (E + 63) / 64;
        k_edges<<<blocks, 256, 0, stream>>>(eidx, P_src, P_dst,
                                            s_src, s_dst, (float*)d_out, E);
    }
}

// Round 14
// 199.807 us; speedup vs baseline: 1.3857x; 1.0223x over previous
//
#include <hip/hip_runtime.h>
#include <hip/hip_fp16.h>
#include <math.h>

#define ALPHA_C 0.5f
#define BETA_C  0.5f
#define NPART   256
#define NQUART  4

typedef _Float16 half8 __attribute__((ext_vector_type(8)));
typedef _Float16 half2v __attribute__((ext_vector_type(2)));
typedef float f32x4 __attribute__((ext_vector_type(4)));

// XOR row-swizzle: spreads a column access across 8 LDS bank-groups.
// XOR mask <= 0x70 and row length 384: bijective within a row.
__device__ __forceinline__ int swz(int row, int byteoff) {
    return byteoff ^ ((row & 7) << 4);
}

// Exact degree histogram with NO global atomics (round-4 design).
__global__ __launch_bounds__(256) void k_hist(
        const int* __restrict__ eidx, unsigned int* __restrict__ scr,
        int N, int E, int Q, int Wd, int chunk) {
    const int s = blockIdx.x;
    const int role = blockIdx.y;
    const int dir = role & 1;
    const int q = role >> 1;
    extern __shared__ unsigned int lds[];          // Wd words
    for (int w = threadIdx.x; w < Wd; w += blockDim.x) lds[w] = 0;
    __syncthreads();
    const int base = q * Q;
    const int hi = min(N - base, Q);
    const int* __restrict__ arr = eidx + (size_t)dir * E;
    const int start = s * chunk;
    const int end = min(E, start + chunk);
    const int4* __restrict__ a4 = (const int4*)arr;
    const int v1 = end >> 2;
    for (int v = (start >> 2) + threadIdx.x; v < v1; v += blockDim.x) {
        int4 x = a4[v];
        int l;
        l = x.x - base; if ((unsigned)l < (unsigned)hi) atomicAdd(&lds[l >> 1], 1u << ((l & 1) * 16));
        l = x.y - base; if ((unsigned)l < (unsigned)hi) atomicAdd(&lds[l >> 1], 1u << ((l & 1) * 16));
        l = x.z - base; if ((unsigned)l < (unsigned)hi) atomicAdd(&lds[l >> 1], 1u << ((l & 1) * 16));
        l = x.w - base; if ((unsigned)l < (unsigned)hi) atomicAdd(&lds[l >> 1], 1u << ((l & 1) * 16));
    }
    for (int i = (v1 << 2) + threadIdx.x; i < end; i += blockDim.x) {
        int l = arr[i] - base;
        if ((unsigned)l < (unsigned)hi) atomicAdd(&lds[l >> 1], 1u << ((l & 1) * 16));
    }
    __syncthreads();
    unsigned int* __restrict__ dst = scr + ((size_t)role * gridDim.x + s) * Wd;
    for (int w = threadIdx.x; w < Wd; w += blockDim.x) dst[w] = lds[w];
}

// Fold slice histograms -> float degrees + sum-of-squares partials.
__global__ __launch_bounds__(256) void k_fold(
        const unsigned int* __restrict__ scr,
        float* __restrict__ deg_out, float* __restrict__ deg_in,
        float* __restrict__ partials, int N, int Q, int Wd, int S) {
    float so = 0.f, si = 0.f;
    for (int n = blockIdx.x * blockDim.x + threadIdx.x; n < N;
         n += gridDim.x * blockDim.x) {
        const int q = n / Q, l = n - q * Q;
        const int w = l >> 1, sh = (l & 1) * 16;
        const unsigned int* __restrict__ p0 = scr + ((size_t)(q * 2 + 0) * S) * Wd + w;
        const unsigned int* __restrict__ p1 = scr + ((size_t)(q * 2 + 1) * S) * Wd + w;
        unsigned int a = 0, b = 0;
        for (int s = 0; s < S; ++s) {
            a += (p0[(size_t)s * Wd] >> sh) & 0xFFFFu;
            b += (p1[(size_t)s * Wd] >> sh) & 0xFFFFu;
        }
        float fa = (float)a, fb = (float)b;
        deg_out[n] = fa;
        deg_in[n] = fb;
        so = fmaf(fa, fa, so);
        si = fmaf(fb, fb, si);
    }
#pragma unroll
    for (int off = 32; off; off >>= 1) {
        so += __shfl_xor(so, off);
        si += __shfl_xor(si, off);
    }
    __shared__ float sm[2][4];
    int lane = threadIdx.x & 63, w = threadIdx.x >> 6;
    if (lane == 0) { sm[0][w] = so; sm[1][w] = si; }
    __syncthreads();
    if (threadIdx.x == 0) {
        partials[blockIdx.x]         = sm[0][0] + sm[0][1] + sm[0][2] + sm[0][3];
        partials[NPART + blockIdx.x] = sm[1][0] + sm[1][1] + sm[1][2] + sm[1][3];
    }
}

// Norm finish + f16 W^T build.
__global__ __launch_bounds__(256) void k_finish(
        const float* __restrict__ partials, float* __restrict__ inv_nrm,
        const float* __restrict__ W_in, const float* __restrict__ W_out,
        _Float16* __restrict__ w16i, _Float16* __restrict__ w16o) {
    int t = threadIdx.x;
    for (int i = t; i < 4096; i += 256) {
        int k = i >> 6, n = i & 63;
        w16o[n * 64 + k] = (_Float16)W_out[k * 64 + n];
        w16i[n * 64 + k] = (_Float16)W_in [k * 64 + n];
    }
    float so = partials[t], si = partials[NPART + t];
#pragma unroll
    for (int off = 32; off; off >>= 1) {
        so += __shfl_xor(so, off);
        si += __shfl_xor(si, off);
    }
    __shared__ float sm[2][4];
    int lane = t & 63, w = t >> 6;
    if (lane == 0) { sm[0][w] = so; sm[1][w] = si; }
    __syncthreads();
    if (t == 0) {
        float a = sm[0][0] + sm[0][1] + sm[0][2] + sm[0][3];
        float b = sm[1][0] + sm[1][1] + sm[1][2] + sm[1][3];
        inv_nrm[0] = (a > 0.f) ? rsqrtf(a) : 0.f;
        inv_nrm[1] = (b > 0.f) ? rsqrtf(b) : 0.f;
    }
}

// MFMA node precompute, LDS-staged. Output: single P array, row n =
// [v_out(64) | z_self(64) | v_in(64)] halfs (384 B). Fragment maps as before.
__global__ __launch_bounds__(256) void k_nodes(
        const float* __restrict__ z_in, const float* __restrict__ z_out,
        const float* __restrict__ z_self,
        const _Float16* __restrict__ w16i, const _Float16* __restrict__ w16o,
        const float* __restrict__ b_in, const float* __restrict__ b_out,
        const float* __restrict__ deg_out, const float* __restrict__ deg_in,
        const float* __restrict__ inv_nrm,
        _Float16* __restrict__ P,
        float* __restrict__ s_src, float* __restrict__ s_dst, int N) {
    __shared__ _Float16 smem[16384];                 // 32 KB
    char* lzo = (char*)smem;                         // [64][64] f16, 8 KB
    char* lzi = (char*)smem + 8192;
    char* lwo = (char*)smem + 16384;                 // W^T [n=64][k=64] f16
    char* lwi = (char*)smem + 24576;
    char* lp  = (char*)smem;                         // [64][384B] P tile (aliases)

    const int tid = threadIdx.x;
    const int lane = tid & 63;
    const int wid = tid >> 6;
    const int r = lane & 15, g = lane >> 4;
    const int base = blockIdx.x * 64;
    const int wrow = wid * 16;

    // ---- phase 1: stage z tiles (cvt) and W^T (16B copies) into LDS ----
#pragma unroll
    for (int it = 0; it < 8; ++it) {
        int flat = it * 256 + tid;                   // [0, 2048)
        int row = flat >> 5;
        int c2 = (flat & 31) * 2;
        int grow = min(base + row, N - 1);
        const float* zr = z_out + (size_t)grow * 65;
        half2v ho = { (_Float16)zr[c2], (_Float16)zr[c2 + 1] };
        *(half2v*)(lzo + row * 128 + swz(row, c2 * 2)) = ho;
        const float* zr2 = z_in + (size_t)grow * 65;
        half2v hi = { (_Float16)zr2[c2], (_Float16)zr2[c2 + 1] };
        *(half2v*)(lzi + row * 128 + swz(row, c2 * 2)) = hi;
    }
#pragma unroll
    for (int it = 0; it < 2; ++it) {
        int flat = it * 256 + tid;                   // [0, 512) 16B chunks
        int n = flat >> 3;
        int c = flat & 7;
        *(half8*)(lwo + n * 128 + swz(n, c * 16)) = *(const half8*)(w16o + flat * 8);
        *(half8*)(lwi + n * 128 + swz(n, c * 16)) = *(const half8*)(w16i + flat * 8);
    }
    half8 bO[2], bI[2];
#pragma unroll
    for (int s = 0; s < 2; ++s)
#pragma unroll
        for (int j = 0; j < 8; ++j) {
            int k = 32 * s + 8 * g + j;
            bO[s][j] = (r == 0) ? (_Float16)b_out[k] : (_Float16)0.f;
            bI[s][j] = (r == 0) ? (_Float16)b_in [k] : (_Float16)0.f;
        }
    __syncthreads();

    // ---- phase 2: fragments from LDS + MFMA ----
    half8 AO[2], AI[2];
#pragma unroll
    for (int s = 0; s < 2; ++s) {
        int arow = wrow + r;
        int off = arow * 128 + swz(arow, s * 64 + g * 16);
        AO[s] = *(half8*)(lzo + off);
        AI[s] = *(half8*)(lzi + off);
    }
    f32x4 aO[4], aI[4], abO = (f32x4)0.f, abI = (f32x4)0.f;
#pragma unroll
    for (int t = 0; t < 4; ++t) { aO[t] = (f32x4)0.f; aI[t] = (f32x4)0.f; }
#pragma unroll
    for (int s = 0; s < 2; ++s) {
#pragma unroll
        for (int t = 0; t < 4; ++t) {
            int n = 16 * t + r;
            int off = n * 128 + swz(n, s * 64 + g * 16);
            half8 BO = *(half8*)(lwo + off);
            aO[t] = __builtin_amdgcn_mfma_f32_16x16x32_f16(AO[s], BO, aO[t], 0, 0, 0);
            half8 BI = *(half8*)(lwi + off);
            aI[t] = __builtin_amdgcn_mfma_f32_16x16x32_f16(AI[s], BI, aI[t], 0, 0, 0);
        }
        abO = __builtin_amdgcn_mfma_f32_16x16x32_f16(AO[s], bO[s], abO, 0, 0, 0);
        abI = __builtin_amdgcn_mfma_f32_16x16x32_f16(AI[s], bI[s], abI, 0, 0, 0);
    }
    __syncthreads();   // lz/lw dead; lp aliases them

    // ---- phase 3: results + z_self into swizzled [64][384B] LDS P tile ----
#pragma unroll
    for (int t = 0; t < 4; ++t)
#pragma unroll
        for (int rr = 0; rr < 4; ++rr) {
            int lrow = wrow + 4 * g + rr;
            int col2 = (16 * t + r) * 2;
            *(_Float16*)(lp + lrow * 384 + swz(lrow, col2)) = (_Float16)aO[t][rr];
            *(_Float16*)(lp + lrow * 384 + swz(lrow, 256 + col2)) = (_Float16)aI[t][rr];
        }
#pragma unroll
    for (int it = 0; it < 8; ++it) {
        int flat = it * 256 + tid;
        int row = flat >> 5;
        int c2 = (flat & 31) * 2;
        int grow = min(base + row, N - 1);
        float2 v = *(const float2*)(z_self + (size_t)grow * 64 + c2);
        half2v h = { (_Float16)v.x, (_Float16)v.y };
        *(half2v*)(lp + row * 384 + swz(row, 128 + c2 * 2)) = h;   // middle third
    }
    if (r == 0) {
        const float i0 = inv_nrm[0], i1 = inv_nrm[1];
#pragma unroll
        for (int rr = 0; rr < 4; ++rr) {
            int m = base + wrow + 4 * g + rr;
            if (m < N) {
                s_src[m] = BETA_C * fmaf(deg_out[m], i0, z_out[(size_t)m * 65 + 64])
                         + ALPHA_C * abO[rr];
                s_dst[m] = BETA_C * fmaf(deg_in[m],  i1, z_in [(size_t)m * 65 + 64])
                         + ALPHA_C * abI[rr];
            }
        }
    }
    __syncthreads();

    // ---- phase 4: coalesced 16B/lane flush (24 chunks per row) ----
#pragma unroll
    for (int it = 0; it < 6; ++it) {
        int flat = it * 256 + tid;                   // [0, 1536)
        int lrow = flat / 24;
        int seg = flat - lrow * 24;
        int m = base + lrow;
        if (m < N) {
            half8 v = *(half8*)(lp + lrow * 384 + swz(lrow, seg * 16));
            *(half8*)(P + (size_t)m * 192 + seg * 8) = v;
        }
    }
}

// Per-edge: 16 lanes per TWO edges. src row = P[s][0:128), dst = P[d][64:192).
__global__ __launch_bounds__(256) void k_edges(
        const int* __restrict__ eidx, const _Float16* __restrict__ P,
        const float* __restrict__ s_src, const float* __restrict__ s_dst,
        float* __restrict__ out, int E) {
    const int sub = threadIdx.x & 15;
    const int grp = blockIdx.x * (blockDim.x >> 4) + (threadIdx.x >> 4);
    const int e0 = grp << 1;
    if (e0 >= E) return;
    const bool has1 = (e0 + 1) < E;
    int2 ss = *(const int2*)(eidx + e0);
    int2 dd = *(const int2*)(eidx + E + e0);
    const int s1 = has1 ? ss.y : ss.x, d1 = has1 ? dd.y : dd.x;
    const uint4 a0 = *(const uint4*)(P + (size_t)ss.x * 192 + sub * 8);
    const uint4 b0 = *(const uint4*)(P + (size_t)dd.x * 192 + 64 + sub * 8);
    const uint4 a1 = *(const uint4*)(P + (size_t)s1 * 192 + sub * 8);
    const uint4 b1 = *(const uint4*)(P + (size_t)d1 * 192 + 64 + sub * 8);
    float ssum = 0.f;
    if (sub < 2) {
        int s = sub ? s1 : ss.x;
        int d = sub ? d1 : dd.x;
        ssum = s_src[s] + s_dst[d];
    }
    float acc0 = 0.f, acc1 = 0.f;
    acc0 = __builtin_amdgcn_fdot2(__builtin_bit_cast(half2v, a0.x), __builtin_bit_cast(half2v, b0.x), acc0, false);
    acc0 = __builtin_amdgcn_fdot2(__builtin_bit_cast(half2v, a0.y), __builtin_bit_cast(half2v, b0.y), acc0, false);
    acc0 = __builtin_amdgcn_fdot2(__builtin_bit_cast(half2v, a0.z), __builtin_bit_cast(half2v, b0.z), acc0, false);
    acc0 = __builtin_amdgcn_fdot2(__builtin_bit_cast(half2v, a0.w), __builtin_bit_cast(half2v, b0.w), acc0, false);
    acc1 = __builtin_amdgcn_fdot2(__builtin_bit_cast(half2v, a1.x), __builtin_bit_cast(half2v, b1.x), acc1, false);
    acc1 = __builtin_amdgcn_fdot2(__builtin_bit_cast(half2v, a1.y), __builtin_bit_cast(half2v, b1.y), acc1, false);
    acc1 = __builtin_amdgcn_fdot2(__builtin_bit_cast(half2v, a1.z), __builtin_bit_cast(half2v, b1.z), acc1, false);
    acc1 = __builtin_amdgcn_fdot2(__builtin_bit_cast(half2v, a1.w), __builtin_bit_cast(half2v, b1.w), acc1, false);
#pragma unroll
    for (int off = 8; off; off >>= 1) {
        acc0 += __shfl_xor(acc0, off);
        acc1 += __shfl_xor(acc1, off);
    }
    if (sub < 2 && (sub == 0 || has1)) {
        float acc = sub ? acc1 : acc0;
        float v = fmaf(ALPHA_C, acc, ssum);
        out[e0 + sub] = 1.0f / (1.0f + __expf(-v));
    }
}

extern "C" void kernel_launch(void* const* d_in, const int* in_sizes, int n_in,
                              void* d_out, int out_size, void* d_ws, size_t ws_size,
                              hipStream_t stream) {
    const float* z_in   = (const float*)d_in[0];
    const float* z_out  = (const float*)d_in[1];
    const float* z_self = (const float*)d_in[2];
    const float* W_in   = (const float*)d_in[3];
    const float* b_in   = (const float*)d_in[4];
    const float* W_out  = (const float*)d_in[5];
    const float* b_out  = (const float*)d_in[6];
    const int*   eidx   = (const int*)d_in[7];

    const int N = in_sizes[2] / 64;   // z_self is [N, 64]
    const int E = in_sizes[7] / 2;    // edge_index is [2, E]

    // Histogram geometry: per-slice edge count < 65536 => u16-exact.
    const int Q = (N + NQUART - 1) / NQUART;
    const int Wd = (Q + 1) / 2;
    int S = (E + 49999) / 50000;
    if (S < 1) S = 1;
    int chunk = ((E + S - 1) / S + 3) & ~3;

    float* ws       = (float*)d_ws;
    float* deg_out  = ws;                             // N
    float* deg_in   = ws + (size_t)N;                 // N
    float* s_src    = ws + 2 * (size_t)N;             // N
    float* s_dst    = ws + 3 * (size_t)N;             // N
    _Float16* P     = (_Float16*)(ws + 4 * (size_t)N);        // N*192 fp16
    float* partials = (float*)(P + (size_t)N * 192);          // 2*NPART
    float* inv_nrm  = partials + 2 * NPART;                   // 2
    _Float16* w16o  = (_Float16*)(inv_nrm + 2 + 12);          // 4096 f16 (16B-aligned)
    _Float16* w16i  = w16o + 4096;                            // 4096 f16
    // scr (hist scratch, ~12.8MB) aliases P region: dead before k_nodes.
    unsigned int* scr = (unsigned int*)P;

    dim3 hgrid(S, 2 * NQUART);
    k_hist<<<hgrid, 256, (size_t)Wd * 4, stream>>>(eidx, scr, N, E, Q, Wd, chunk);
    k_fold<<<NPART, 256, 0, stream>>>(scr, deg_out, deg_in, partials, N, Q, Wd, S);
    k_finish<<<1, 256, 0, stream>>>(partials, inv_nrm, W_in, W_out, w16i, w16o);
    k_nodes<<<(N + 63) / 64, 256, 0, stream>>>(z_in, z_out, z_self, w16i, w16o,
                                               b_in, b_out, deg_out, deg_in,
                                               inv_nrm, P, s_src, s_dst, N);
    {
        int groups = (E + 1) / 2;
        int blocks = (groups + 15) / 16;
        k_edges<<<blocks, 256, 0, stream>>>(eidx, P, s_src, s_dst,
                                            (float*)d_out, E);
    }
}

// Round 15
// 197.113 us; speedup vs baseline: 1.4046x; 1.0137x over previous
//
#include <hip/hip_runtime.h>
#include <hip/hip_fp16.h>
#include <math.h>

#define ALPHA_C 0.5f
#define BETA_C  0.5f
#define NPART   256
#define NQUART  4

typedef _Float16 half8 __attribute__((ext_vector_type(8)));
typedef _Float16 half4v __attribute__((ext_vector_type(4)));
typedef _Float16 half2v __attribute__((ext_vector_type(2)));
typedef float f32x4 __attribute__((ext_vector_type(4)));

// XOR row-swizzle: spreads a column access across 8 LDS bank-groups.
__device__ __forceinline__ int swz(int row, int byteoff) {
    return byteoff ^ ((row & 7) << 4);
}

// Exact degree histogram with NO global atomics (round-4 design).
__global__ __launch_bounds__(256) void k_hist(
        const int* __restrict__ eidx, unsigned int* __restrict__ scr,
        int N, int E, int Q, int Wd, int chunk) {
    const int s = blockIdx.x;
    const int role = blockIdx.y;
    const int dir = role & 1;
    const int q = role >> 1;
    extern __shared__ unsigned int lds[];          // Wd words
    for (int w = threadIdx.x; w < Wd; w += blockDim.x) lds[w] = 0;
    __syncthreads();
    const int base = q * Q;
    const int hi = min(N - base, Q);
    const int* __restrict__ arr = eidx + (size_t)dir * E;
    const int start = s * chunk;
    const int end = min(E, start + chunk);
    const int4* __restrict__ a4 = (const int4*)arr;
    const int v1 = end >> 2;
    for (int v = (start >> 2) + threadIdx.x; v < v1; v += blockDim.x) {
        int4 x = a4[v];
        int l;
        l = x.x - base; if ((unsigned)l < (unsigned)hi) atomicAdd(&lds[l >> 1], 1u << ((l & 1) * 16));
        l = x.y - base; if ((unsigned)l < (unsigned)hi) atomicAdd(&lds[l >> 1], 1u << ((l & 1) * 16));
        l = x.z - base; if ((unsigned)l < (unsigned)hi) atomicAdd(&lds[l >> 1], 1u << ((l & 1) * 16));
        l = x.w - base; if ((unsigned)l < (unsigned)hi) atomicAdd(&lds[l >> 1], 1u << ((l & 1) * 16));
    }
    for (int i = (v1 << 2) + threadIdx.x; i < end; i += blockDim.x) {
        int l = arr[i] - base;
        if ((unsigned)l < (unsigned)hi) atomicAdd(&lds[l >> 1], 1u << ((l & 1) * 16));
    }
    __syncthreads();
    unsigned int* __restrict__ dst = scr + ((size_t)role * gridDim.x + s) * Wd;
    for (int w = threadIdx.x; w < Wd; w += blockDim.x) dst[w] = lds[w];
}

// Fold slice histograms -> degrees + sum-of-squares partials.
// Also: streams z_self into P's middle third (pure-BW job moved out of
// k_nodes), and block 0 builds the f16 W^T arrays.
__global__ __launch_bounds__(256) void k_fold(
        const unsigned int* __restrict__ scr,
        float* __restrict__ deg_out, float* __restrict__ deg_in,
        float* __restrict__ partials,
        const float* __restrict__ z_self, _Float16* __restrict__ P,
        const float* __restrict__ W_in, const float* __restrict__ W_out,
        _Float16* __restrict__ w16i, _Float16* __restrict__ w16o,
        int N, int Q, int Wd, int S) {
    float so = 0.f, si = 0.f;
    for (int n = blockIdx.x * blockDim.x + threadIdx.x; n < N;
         n += gridDim.x * blockDim.x) {
        const int q = n / Q, l = n - q * Q;
        const int w = l >> 1, sh = (l & 1) * 16;
        const unsigned int* __restrict__ p0 = scr + ((size_t)(q * 2 + 0) * S) * Wd + w;
        const unsigned int* __restrict__ p1 = scr + ((size_t)(q * 2 + 1) * S) * Wd + w;
        unsigned int a = 0, b = 0;
        for (int s = 0; s < S; ++s) {
            a += (p0[(size_t)s * Wd] >> sh) & 0xFFFFu;
            b += (p1[(size_t)s * Wd] >> sh) & 0xFFFFu;
        }
        float fa = (float)a, fb = (float)b;
        deg_out[n] = fa;
        deg_in[n] = fb;
        so = fmaf(fa, fa, so);
        si = fmaf(fb, fb, si);
    }
    // z_self -> P[:, 64:128) halfs (middle third), coalesced streaming.
    const int total = N * 16;
    for (int c = blockIdx.x * blockDim.x + threadIdx.x; c < total;
         c += gridDim.x * blockDim.x) {
        int row = c >> 4, c4 = c & 15;
        f32x4 v = *(const f32x4*)(z_self + (size_t)row * 64 + c4 * 4);
        half4v h = { (_Float16)v.x, (_Float16)v.y,
                     (_Float16)v.z, (_Float16)v.w };
        *(half4v*)(P + (size_t)row * 192 + 64 + c4 * 4) = h;
    }
    // block 0: f16 W^T build (tiny)
    if (blockIdx.x == 0) {
        for (int i = threadIdx.x; i < 4096; i += 256) {
            int k = i >> 6, n = i & 63;
            w16o[n * 64 + k] = (_Float16)W_out[k * 64 + n];
            w16i[n * 64 + k] = (_Float16)W_in [k * 64 + n];
        }
    }
#pragma unroll
    for (int off = 32; off; off >>= 1) {
        so += __shfl_xor(so, off);
        si += __shfl_xor(si, off);
    }
    __shared__ float sm[2][4];
    int lane = threadIdx.x & 63, w = threadIdx.x >> 6;
    if (lane == 0) { sm[0][w] = so; sm[1][w] = si; }
    __syncthreads();
    if (threadIdx.x == 0) {
        partials[blockIdx.x]         = sm[0][0] + sm[0][1] + sm[0][2] + sm[0][3];
        partials[NPART + blockIdx.x] = sm[1][0] + sm[1][1] + sm[1][2] + sm[1][3];
    }
}

// Norm finish only.
__global__ __launch_bounds__(256) void k_finish(
        const float* __restrict__ partials, float* __restrict__ inv_nrm) {
    int t = threadIdx.x;
    float so = partials[t], si = partials[NPART + t];
#pragma unroll
    for (int off = 32; off; off >>= 1) {
        so += __shfl_xor(so, off);
        si += __shfl_xor(si, off);
    }
    __shared__ float sm[2][4];
    int lane = t & 63, w = t >> 6;
    if (lane == 0) { sm[0][w] = so; sm[1][w] = si; }
    __syncthreads();
    if (t == 0) {
        float a = sm[0][0] + sm[0][1] + sm[0][2] + sm[0][3];
        float b = sm[1][0] + sm[1][1] + sm[1][2] + sm[1][3];
        inv_nrm[0] = (a > 0.f) ? rsqrtf(a) : 0.f;
        inv_nrm[1] = (b > 0.f) ? rsqrtf(b) : 0.f;
    }
}

// MFMA node precompute, LDS-staged. Writes P outer thirds only:
// row n = [v_out(64) | (z_self, written by k_fold) | v_in(64)].
// Fragment maps (verified rounds 5-14):
//   A[m][k]: m = lane&15, k = 32*s + 8*(lane>>4) + j
//   B[k][n]: n = lane&15, k = 32*s + 8*(lane>>4) + j  (w16 = W^T [n][k])
//   D[m][n]: n = lane&15, m = 4*(lane>>4) + reg
__global__ __launch_bounds__(256) void k_nodes(
        const float* __restrict__ z_in, const float* __restrict__ z_out,
        const _Float16* __restrict__ w16i, const _Float16* __restrict__ w16o,
        const float* __restrict__ b_in, const float* __restrict__ b_out,
        const float* __restrict__ deg_out, const float* __restrict__ deg_in,
        const float* __restrict__ inv_nrm,
        _Float16* __restrict__ P,
        float* __restrict__ s_src, float* __restrict__ s_dst, int N) {
    __shared__ _Float16 smem[16384];                 // 32 KB
    char* lzo = (char*)smem;                         // [64][64] f16, 8 KB
    char* lzi = (char*)smem + 8192;
    char* lwo = (char*)smem + 16384;                 // W^T [n=64][k=64] f16
    char* lwi = (char*)smem + 24576;
    char* lp  = (char*)smem;                         // [64][256B] results (aliases z)

    const int tid = threadIdx.x;
    const int lane = tid & 63;
    const int wid = tid >> 6;
    const int r = lane & 15, g = lane >> 4;
    const int base = blockIdx.x * 64;
    const int wrow = wid * 16;

    // ---- phase 1: stage z tiles (cvt) and W^T (16B copies) into LDS ----
#pragma unroll
    for (int it = 0; it < 8; ++it) {
        int flat = it * 256 + tid;                   // [0, 2048)
        int row = flat >> 5;
        int c2 = (flat & 31) * 2;
        int grow = min(base + row, N - 1);
        const float* zr = z_out + (size_t)grow * 65;
        half2v ho = { (_Float16)zr[c2], (_Float16)zr[c2 + 1] };
        *(half2v*)(lzo + row * 128 + swz(row, c2 * 2)) = ho;
        const float* zr2 = z_in + (size_t)grow * 65;
        half2v hi = { (_Float16)zr2[c2], (_Float16)zr2[c2 + 1] };
        *(half2v*)(lzi + row * 128 + swz(row, c2 * 2)) = hi;
    }
#pragma unroll
    for (int it = 0; it < 2; ++it) {
        int flat = it * 256 + tid;                   // [0, 512) 16B chunks
        int n = flat >> 3;
        int c = flat & 7;
        *(half8*)(lwo + n * 128 + swz(n, c * 16)) = *(const half8*)(w16o + flat * 8);
        *(half8*)(lwi + n * 128 + swz(n, c * 16)) = *(const half8*)(w16i + flat * 8);
    }
    half8 bO[2], bI[2];
#pragma unroll
    for (int s = 0; s < 2; ++s)
#pragma unroll
        for (int j = 0; j < 8; ++j) {
            int k = 32 * s + 8 * g + j;
            bO[s][j] = (r == 0) ? (_Float16)b_out[k] : (_Float16)0.f;
            bI[s][j] = (r == 0) ? (_Float16)b_in [k] : (_Float16)0.f;
        }
    __syncthreads();

    // ---- phase 2: fragments from LDS + MFMA ----
    half8 AO[2], AI[2];
#pragma unroll
    for (int s = 0; s < 2; ++s) {
        int arow = wrow + r;
        int off = arow * 128 + swz(arow, s * 64 + g * 16);
        AO[s] = *(half8*)(lzo + off);
        AI[s] = *(half8*)(lzi + off);
    }
    f32x4 aO[4], aI[4], abO = (f32x4)0.f, abI = (f32x4)0.f;
#pragma unroll
    for (int t = 0; t < 4; ++t) { aO[t] = (f32x4)0.f; aI[t] = (f32x4)0.f; }
#pragma unroll
    for (int s = 0; s < 2; ++s) {
#pragma unroll
        for (int t = 0; t < 4; ++t) {
            int n = 16 * t + r;
            int off = n * 128 + swz(n, s * 64 + g * 16);
            half8 BO = *(half8*)(lwo + off);
            aO[t] = __builtin_amdgcn_mfma_f32_16x16x32_f16(AO[s], BO, aO[t], 0, 0, 0);
            half8 BI = *(half8*)(lwi + off);
            aI[t] = __builtin_amdgcn_mfma_f32_16x16x32_f16(AI[s], BI, aI[t], 0, 0, 0);
        }
        abO = __builtin_amdgcn_mfma_f32_16x16x32_f16(AO[s], bO[s], abO, 0, 0, 0);
        abI = __builtin_amdgcn_mfma_f32_16x16x32_f16(AI[s], bI[s], abI, 0, 0, 0);
    }
    __syncthreads();   // z tiles dead; lp aliases them

    // ---- phase 3: results into swizzled [64][256B] LDS tile ----
    // layout: bytes [0,128) = v_out, [128,256) = v_in
#pragma unroll
    for (int t = 0; t < 4; ++t)
#pragma unroll
        for (int rr = 0; rr < 4; ++rr) {
            int lrow = wrow + 4 * g + rr;
            int col2 = (16 * t + r) * 2;
            *(_Float16*)(lp + lrow * 256 + swz(lrow, col2)) = (_Float16)aO[t][rr];
            *(_Float16*)(lp + lrow * 256 + swz(lrow, 128 + col2)) = (_Float16)aI[t][rr];
        }
    if (r == 0) {
        const float i0 = inv_nrm[0], i1 = inv_nrm[1];
#pragma unroll
        for (int rr = 0; rr < 4; ++rr) {
            int m = base + wrow + 4 * g + rr;
            if (m < N) {
                s_src[m] = BETA_C * fmaf(deg_out[m], i0, z_out[(size_t)m * 65 + 64])
                         + ALPHA_C * abO[rr];
                s_dst[m] = BETA_C * fmaf(deg_in[m],  i1, z_in [(size_t)m * 65 + 64])
                         + ALPHA_C * abI[rr];
            }
        }
    }
    __syncthreads();

    // ---- phase 4: coalesced 16B/lane flush of the two outer thirds ----
#pragma unroll
    for (int it = 0; it < 4; ++it) {
        int flat = it * 256 + tid;                   // [0, 1024)
        int lrow = flat >> 4;
        int seg = flat & 15;                         // 0..7 v_out, 8..15 v_in
        int m = base + lrow;
        if (m < N) {
            half8 v = *(half8*)(lp + lrow * 256 + swz(lrow, seg * 16));
            int hoff = seg * 8 + ((seg >> 3) << 6);  // [0,64) or [128,192)
            *(half8*)(P + (size_t)m * 192 + hoff) = v;
        }
    }
}

// Per-edge: 16 lanes per TWO edges. src row = P[s][0:128), dst = P[d][64:192).
__global__ __launch_bounds__(256) void k_edges(
        const int* __restrict__ eidx, const _Float16* __restrict__ P,
        const float* __restrict__ s_src, const float* __restrict__ s_dst,
        float* __restrict__ out, int E) {
    const int sub = threadIdx.x & 15;
    const int grp = blockIdx.x * (blockDim.x >> 4) + (threadIdx.x >> 4);
    const int e0 = grp << 1;
    if (e0 >= E) return;
    const bool has1 = (e0 + 1) < E;
    int2 ss = *(const int2*)(eidx + e0);
    int2 dd = *(const int2*)(eidx + E + e0);
    const int s1 = has1 ? ss.y : ss.x, d1 = has1 ? dd.y : dd.x;
    const uint4 a0 = *(const uint4*)(P + (size_t)ss.x * 192 + sub * 8);
    const uint4 b0 = *(const uint4*)(P + (size_t)dd.x * 192 + 64 + sub * 8);
    const uint4 a1 = *(const uint4*)(P + (size_t)s1 * 192 + sub * 8);
    const uint4 b1 = *(const uint4*)(P + (size_t)d1 * 192 + 64 + sub * 8);
    float ssum = 0.f;
    if (sub < 2) {
        int s = sub ? s1 : ss.x;
        int d = sub ? d1 : dd.x;
        ssum = s_src[s] + s_dst[d];
    }
    float acc0 = 0.f, acc1 = 0.f;
    acc0 = __builtin_amdgcn_fdot2(__builtin_bit_cast(half2v, a0.x), __builtin_bit_cast(half2v, b0.x), acc0, false);
    acc0 = __builtin_amdgcn_fdot2(__builtin_bit_cast(half2v, a0.y), __builtin_bit_cast(half2v, b0.y), acc0, false);
    acc0 = __builtin_amdgcn_fdot2(__builtin_bit_cast(half2v, a0.z), __builtin_bit_cast(half2v, b0.z), acc0, false);
    acc0 = __builtin_amdgcn_fdot2(__builtin_bit_cast(half2v, a0.w), __builtin_bit_cast(half2v, b0.w), acc0, false);
    acc1 = __builtin_amdgcn_fdot2(__builtin_bit_cast(half2v, a1.x), __builtin_bit_cast(half2v, b1.x), acc1, false);
    acc1 = __builtin_amdgcn_fdot2(__builtin_bit_cast(half2v, a1.y), __builtin_bit_cast(half2v, b1.y), acc1, false);
    acc1 = __builtin_amdgcn_fdot2(__builtin_bit_cast(half2v, a1.z), __builtin_bit_cast(half2v, b1.z), acc1, false);
    acc1 = __builtin_amdgcn_fdot2(__builtin_bit_cast(half2v, a1.w), __builtin_bit_cast(half2v, b1.w), acc1, false);
#pragma unroll
    for (int off = 8; off; off >>= 1) {
        acc0 += __shfl_xor(acc0, off);
        acc1 += __shfl_xor(acc1, off);
    }
    if (sub < 2 && (sub == 0 || has1)) {
        float acc = sub ? acc1 : acc0;
        float v = fmaf(ALPHA_C, acc, ssum);
        out[e0 + sub] = 1.0f / (1.0f + __expf(-v));
    }
}

extern "C" void kernel_launch(void* const* d_in, const int* in_sizes, int n_in,
                              void* d_out, int out_size, void* d_ws, size_t ws_size,
                              hipStream_t stream) {
    const float* z_in   = (const float*)d_in[0];
    const float* z_out  = (const float*)d_in[1];
    const float* z_self = (const float*)d_in[2];
    const float* W_in   = (const float*)d_in[3];
    const float* b_in   = (const float*)d_in[4];
    const float* W_out  = (const float*)d_in[5];
    const float* b_out  = (const float*)d_in[6];
    const int*   eidx   = (const int*)d_in[7];

    const int N = in_sizes[2] / 64;   // z_self is [N, 64]
    const int E = in_sizes[7] / 2;    // edge_index is [2, E]

    // Histogram geometry: per-slice edge count < 65536 => u16-exact.
    const int Q = (N + NQUART - 1) / NQUART;
    const int Wd = (Q + 1) / 2;
    int S = (E + 49999) / 50000;
    if (S < 1) S = 1;
    int chunk = ((E + S - 1) / S + 3) & ~3;

    float* ws       = (float*)d_ws;
    float* deg_out  = ws;                             // N
    float* deg_in   = ws + (size_t)N;                 // N
    float* s_src    = ws + 2 * (size_t)N;             // N
    float* s_dst    = ws + 3 * (size_t)N;             // N
    _Float16* P     = (_Float16*)(ws + 4 * (size_t)N);        // N*192 fp16
    float* partials = (float*)(P + (size_t)N * 192);          // 2*NPART
    float* inv_nrm  = partials + 2 * NPART;                   // 2
    _Float16* w16o  = (_Float16*)(inv_nrm + 2 + 12);          // 4096 f16 (16B-aligned)
    _Float16* w16i  = w16o + 4096;                            // 4096 f16
    // scr now DISJOINT from P (k_fold writes P while reading scr).
    unsigned int* scr = (unsigned int*)(w16i + 4096);         // 8*S*Wd words

    dim3 hgrid(S, 2 * NQUART);
    k_hist<<<hgrid, 256, (size_t)Wd * 4, stream>>>(eidx, scr, N, E, Q, Wd, chunk);
    k_fold<<<NPART, 256, 0, stream>>>(scr, deg_out, deg_in, partials,
                                      z_self, P, W_in, W_out, w16i, w16o,
                                      N, Q, Wd, S);
    k_finish<<<1, 256, 0, stream>>>(partials, inv_nrm);
    k_nodes<<<(N + 63) / 64, 256, 0, stream>>>(z_in, z_out, w16i, w16o,
                                               b_in, b_out, deg_out, deg_in,
                                               inv_nrm, P, s_src, s_dst, N);
    {
        int groups = (E + 1) / 2;
        int blocks = (groups + 15) / 16;
        k_edges<<<blocks, 256, 0, stream>>>(eidx, P, s_src, s_dst,
                                            (float*)d_out, E);
    }
}